// Round 6
// baseline (379.285 us; speedup 1.0000x reference)
//
#include <hip/hip_runtime.h>
#include <math.h>

// N=50000 nodes, E0=800000 edges (+N self loops), IN=128, H=8, C=8 (HC=64), ED=16, T=96

struct __align__(8) US4 { unsigned short x, y, z, w; };

__device__ __forceinline__ unsigned short f2bf(float f) {
    unsigned u = __float_as_uint(f);
    unsigned r = (u + 0x7fffu + ((u >> 16) & 1u)) >> 16;
    return (unsigned short)r;
}
__device__ __forceinline__ float bf2f(unsigned short u) {
    return __uint_as_float(((unsigned)u) << 16);
}
__device__ __forceinline__ float blo(unsigned u) { return __uint_as_float(u << 16); }
__device__ __forceinline__ float bhi(unsigned u) { return __uint_as_float(u & 0xffff0000u); }

// ---------------- node projections: q (f32, pre-scaled 1/sqrt8), k,v (bf16), an,bn (f32) ----
__global__ __launch_bounds__(256) void k_proj(
    const float* __restrict__ x,
    const float* __restrict__ Wq, const float* __restrict__ Wk, const float* __restrict__ Wv,
    const float* __restrict__ compW, const float* __restrict__ compb,
    float* __restrict__ q, unsigned short* __restrict__ kb, unsigned short* __restrict__ vb,
    float* __restrict__ an, float* __restrict__ bn, int N)
{
    __shared__ float xt[64 * 128];
    const int n0 = blockIdx.x * 64;
    const int tid = threadIdx.x;
    for (int i = tid; i < 2048; i += 256) {
        int row = i >> 5, c4 = i & 31;
        int n = n0 + row;
        float4 val = make_float4(0.f, 0.f, 0.f, 0.f);
        if (n < N) val = ((const float4*)(x + (size_t)n * 128))[c4];
        ((float4*)xt)[i] = val;
    }
    __syncthreads();
    if (tid >= 208) return;
    const int sh = tid / 52;          // node quarter (16 nodes)
    const int cq = tid % 52;          // column quad

    const float* wrow; int wstride;
    if (cq < 16)      { wrow = Wq + (size_t)cq * 4 * 128;          wstride = 128; }
    else if (cq < 32) { wrow = Wk + (size_t)(cq - 16) * 4 * 128;   wstride = 128; }
    else if (cq < 48) { wrow = Wv + (size_t)(cq - 32) * 4 * 128;   wstride = 128; }
    else if (cq < 50) { wrow = compW + (size_t)(cq - 48) * 4 * 256;       wstride = 256; }
    else              { wrow = compW + (size_t)(cq - 50) * 4 * 256 + 128; wstride = 256; }

    float acc[16][4];
    #pragma unroll
    for (int i = 0; i < 16; i++)
        #pragma unroll
        for (int j = 0; j < 4; j++) acc[i][j] = 0.f;

    const float4* xt4 = (const float4*)xt;
    for (int k4 = 0; k4 < 32; k4++) {
        float4 w0 = ((const float4*)(wrow + 0 * wstride))[k4];
        float4 w1 = ((const float4*)(wrow + 1 * wstride))[k4];
        float4 w2 = ((const float4*)(wrow + 2 * wstride))[k4];
        float4 w3 = ((const float4*)(wrow + 3 * wstride))[k4];
        #pragma unroll
        for (int nn = 0; nn < 16; nn++) {
            float4 x4 = xt4[(sh * 16 + nn) * 32 + k4];
            acc[nn][0] += x4.x * w0.x + x4.y * w0.y + x4.z * w0.z + x4.w * w0.w;
            acc[nn][1] += x4.x * w1.x + x4.y * w1.y + x4.z * w1.z + x4.w * w1.w;
            acc[nn][2] += x4.x * w2.x + x4.y * w2.y + x4.z * w2.z + x4.w * w2.w;
            acc[nn][3] += x4.x * w3.x + x4.y * w3.y + x4.z * w3.z + x4.w * w3.w;
        }
    }
    #pragma unroll
    for (int nn = 0; nn < 16; nn++) {
        int n = n0 + sh * 16 + nn;
        if (n >= N) continue;
        if (cq < 16) {
            const float qs = 0.35355339059327373f;
            float4 r = make_float4(acc[nn][0] * qs, acc[nn][1] * qs,
                                   acc[nn][2] * qs, acc[nn][3] * qs);
            ((float4*)(q + (size_t)n * 64))[cq] = r;
        } else if (cq < 32) {
            US4 u = { f2bf(acc[nn][0]), f2bf(acc[nn][1]), f2bf(acc[nn][2]), f2bf(acc[nn][3]) };
            ((US4*)(kb + (size_t)n * 64))[cq - 16] = u;
        } else if (cq < 48) {
            US4 u = { f2bf(acc[nn][0]), f2bf(acc[nn][1]), f2bf(acc[nn][2]), f2bf(acc[nn][3]) };
            ((US4*)(vb + (size_t)n * 64))[cq - 32] = u;
        } else if (cq < 50) {
            float4 r = make_float4(acc[nn][0], acc[nn][1], acc[nn][2], acc[nn][3]);
            ((float4*)(an + (size_t)n * 8))[cq - 48] = r;
        } else {
            int c0 = (cq - 50) * 4;
            float4 r = make_float4(acc[nn][0] + compb[c0],     acc[nn][1] + compb[c0 + 1],
                                   acc[nn][2] + compb[c0 + 2], acc[nn][3] + compb[c0 + 3]);
            ((float4*)(bn + (size_t)n * 8))[cq - 50] = r;
        }
    }
}

// ---------------- G precompute: G[s][h][d] = sum_c We[h*8+c][d] * k[s][h*8+c] (bf16) --------
__global__ __launch_bounds__(256) void k_G(
    const unsigned short* __restrict__ kb, const float* __restrict__ We,
    unsigned short* __restrict__ Gb, int N)
{
    __shared__ float WeS[1024];      // We[hc][d], 64x16
    const int tid = threadIdx.x;
    for (int i = tid; i < 1024; i += 256) WeS[i] = We[i];
    __syncthreads();
    int gid = blockIdx.x * 256 + tid;
    if (gid >= N * 128) return;
    int s = gid >> 7, hd = gid & 127, h = hd >> 4, d = hd & 15;
    const US4* kp = (const US4*)(kb + (size_t)s * 64 + h * 8);
    US4 k0 = kp[0], k1 = kp[1];
    const float* w = WeS + (h * 8) * 16 + d;
    float g = bf2f(k0.x) * w[0]   + bf2f(k0.y) * w[16]  + bf2f(k0.z) * w[32]  + bf2f(k0.w) * w[48]
            + bf2f(k1.x) * w[64]  + bf2f(k1.y) * w[80]  + bf2f(k1.z) * w[96]  + bf2f(k1.w) * w[112];
    Gb[(size_t)s * 128 + hd] = f2bf(g);
}

// ---------------- temporal profile normalization (ddof=1) -> bf16, one wave per node ----------
__global__ __launch_bounds__(256) void k_tpn(const float* __restrict__ tp,
                                             unsigned short* __restrict__ tpnb, int N)
{
    int wave = threadIdx.x >> 6;
    int lane = threadIdx.x & 63;
    int n = blockIdx.x * 4 + wave;
    if (n >= N) return;
    const float* row = tp + (size_t)n * 96;
    float v0 = row[lane];
    float v1 = (lane < 32) ? row[64 + lane] : 0.f;
    float s = v0 + v1, ss = v0 * v0 + v1 * v1;
    #pragma unroll
    for (int m = 1; m < 64; m <<= 1) { s += __shfl_xor(s, m); ss += __shfl_xor(ss, m); }
    float mean = s * (1.f / 96.f);
    float var = (ss - 96.f * mean * mean) * (1.f / 95.f);
    var = fmaxf(var, 0.f);
    float inv = 1.f / (sqrtf(var) + 1e-8f);
    unsigned short* orow = tpnb + (size_t)n * 96;
    orow[lane] = f2bf((v0 - mean) * inv);
    if (lane < 32) orow[64 + lane] = f2bf((v1 - mean) * inv);
}

// ---------------- CSR build: histogram / 3-stage scan / scatter ----------------
__global__ __launch_bounds__(256) void k_hist(const int* __restrict__ ei,
                                              int* __restrict__ deg, int E0, int N)
{
    int e = blockIdx.x * 256 + threadIdx.x;
    int E = E0 + N;
    if (e >= E) return;
    int dst = (e < E0) ? ei[E0 + e] : (e - E0);
    atomicAdd(&deg[dst], 1);
}

__global__ __launch_bounds__(256) void k_scanA(const int* __restrict__ deg,
                                               int* __restrict__ bsum, int N)
{
    __shared__ int sm[256];
    int i = blockIdx.x * 256 + threadIdx.x;
    sm[threadIdx.x] = (i < N) ? deg[i] : 0;
    __syncthreads();
    for (int off = 128; off > 0; off >>= 1) {
        if (threadIdx.x < off) sm[threadIdx.x] += sm[threadIdx.x + off];
        __syncthreads();
    }
    if (threadIdx.x == 0) bsum[blockIdx.x] = sm[0];
}

__global__ __launch_bounds__(256) void k_scanB(int* __restrict__ bsum, int NB)
{
    __shared__ int sm[256];
    int t = threadIdx.x;
    sm[t] = (t < NB) ? bsum[t] : 0;
    __syncthreads();
    for (int off = 1; off < 256; off <<= 1) {
        int v = (t >= off) ? sm[t - off] : 0;
        __syncthreads();
        sm[t] += v;
        __syncthreads();
    }
    if (t < NB) bsum[t] = (t == 0) ? 0 : sm[t - 1];
}

__global__ __launch_bounds__(256) void k_scanC(const int* __restrict__ deg,
                                               const int* __restrict__ bsum,
                                               int* __restrict__ row,
                                               int* __restrict__ cursor, int N)
{
    __shared__ int sm[256];
    int b = blockIdx.x, t = threadIdx.x, i = b * 256 + t;
    int v = (i < N) ? deg[i] : 0;
    sm[t] = v;
    __syncthreads();
    for (int off = 1; off < 256; off <<= 1) {
        int u = (t >= off) ? sm[t - off] : 0;
        __syncthreads();
        sm[t] += u;
        __syncthreads();
    }
    int excl = bsum[b] + sm[t] - v;
    if (i < N) {
        row[i] = excl;
        cursor[i] = excl;
        if (i == N - 1) row[N] = excl + v;
    }
}

__global__ __launch_bounds__(256) void k_scatter(const int* __restrict__ ei,
                                                 int* __restrict__ cursor,
                                                 int2* __restrict__ csrp,
                                                 int* __restrict__ dstA, int E0, int N)
{
    int e = blockIdx.x * 256 + threadIdx.x;
    int E = E0 + N;
    if (e >= E) return;
    int src, dst;
    if (e < E0) { src = ei[e]; dst = ei[E0 + e]; }
    else        { src = e - E0; dst = src; }
    int pos = atomicAdd(&cursor[dst], 1);
    csrp[pos] = make_int2(e, src);
    dstA[pos] = dst;
}

// ---------------- edge-parallel logits (CSR order): 8 lanes per edge, lane = head ----------
__global__ __launch_bounds__(256) void k_logits(
    const int2* __restrict__ csrp, const int* __restrict__ dstA,
    const float* __restrict__ eattr,
    const unsigned short* __restrict__ tpnb, const float* __restrict__ q,
    const unsigned short* __restrict__ kb, const unsigned short* __restrict__ Gb,
    const float* __restrict__ an, const float* __restrict__ bn,
    float* __restrict__ alpha, int E0, int E)
{
    const int tid = threadIdx.x;
    const int idx = blockIdx.x * 32 + (tid >> 3);
    if (idx >= E) return;
    const int h = tid & 7;
    int2 es = csrp[idx];
    const int e = es.x, s = es.y;
    const int d = dstA[idx];

    // qk (q pre-scaled by 1/sqrt8)
    const float4* qp = (const float4*)(q + (size_t)d * 64 + h * 8);
    float4 q0 = qp[0], q1 = qp[1];
    const US4* kp = (const US4*)(kb + (size_t)s * 64 + h * 8);
    US4 k0 = kp[0], k1 = kp[1];
    float qk = q0.x * bf2f(k0.x) + q0.y * bf2f(k0.y) + q0.z * bf2f(k0.z) + q0.w * bf2f(k0.w)
             + q1.x * bf2f(k1.x) + q1.y * bf2f(k1.y) + q1.z * bf2f(k1.z) + q1.w * bf2f(k1.w);

    // efk = sum_d ea[d] * G[s][h][d]
    const uint4* gp = (const uint4*)(Gb + (size_t)s * 128 + h * 16);
    uint4 g0 = gp[0], g1 = gp[1];
    float gv[16];
    gv[0] = blo(g0.x); gv[1] = bhi(g0.x); gv[2]  = blo(g0.y); gv[3]  = bhi(g0.y);
    gv[4] = blo(g0.z); gv[5] = bhi(g0.z); gv[6]  = blo(g0.w); gv[7]  = bhi(g0.w);
    gv[8] = blo(g1.x); gv[9] = bhi(g1.x); gv[10] = blo(g1.y); gv[11] = bhi(g1.y);
    gv[12] = blo(g1.z); gv[13] = bhi(g1.z); gv[14] = blo(g1.w); gv[15] = bhi(g1.w);
    float efk;
    if (e < E0) {
        const float4* ep = (const float4*)(eattr + (size_t)e * 16);
        float4 e0 = ep[0], e1 = ep[1], e2 = ep[2], e3 = ep[3];
        efk = e0.x * gv[0]  + e0.y * gv[1]  + e0.z * gv[2]  + e0.w * gv[3]
            + e1.x * gv[4]  + e1.y * gv[5]  + e1.z * gv[6]  + e1.w * gv[7]
            + e2.x * gv[8]  + e2.y * gv[9]  + e2.z * gv[10] + e2.w * gv[11]
            + e3.x * gv[12] + e3.y * gv[13] + e3.z * gv[14] + e3.w * gv[15];
    } else {
        efk = (gv[0] + gv[1]) + (gv[2] + gv[3]) + (gv[4] + gv[5]) + (gv[6] + gv[7])
            + (gv[8] + gv[9]) + (gv[10] + gv[11]) + (gv[12] + gv[13]) + (gv[14] + gv[15]);
    }

    // tanh term (bn already includes comp_b)
    float tv = an[(size_t)s * 8 + h] + bn[(size_t)d * 8 + h];
    float ex = __expf(2.f * tv);
    float t = 1.f - 2.f / (ex + 1.f);

    // correlation partial: lane h covers t-range [12h, 12h+12)
    const uint2* tsp = (const uint2*)(tpnb + (size_t)s * 96 + h * 12);
    const uint2* tdp = (const uint2*)(tpnb + (size_t)d * 96 + h * 12);
    float pc = 0.f;
    #pragma unroll
    for (int i = 0; i < 3; i++) {
        uint2 us = tsp[i], ud = tdp[i];
        pc += blo(us.x) * blo(ud.x) + bhi(us.x) * bhi(ud.x)
            + blo(us.y) * blo(ud.y) + bhi(us.y) * bhi(ud.y);
    }
    // combined comp contribution: -0.25*corr - 0.25*learned
    float cv = pc * (-0.25f / 96.f) + t * (-0.25f / 8.f);
    cv += __shfl_xor(cv, 1); cv += __shfl_xor(cv, 2); cv += __shfl_xor(cv, 4);

    float a = qk + efk + cv;
    a = fmaxf(a, 0.2f * a);                     // leaky relu
    alpha[(size_t)idx * 8 + h] = a;
}

// ---------------- per-node: softmax over CSR-ordered alpha + V agg + Wo ----------------
__global__ __launch_bounds__(256) void k_agg(
    const int2* __restrict__ csrp, const int* __restrict__ row,
    const float* __restrict__ alpha, const unsigned short* __restrict__ vb,
    const float* __restrict__ Wo, const float* __restrict__ bo,
    float* __restrict__ out, int N)
{
    const int tid = threadIdx.x;
    const int wave = tid >> 6, lane = tid & 63;
    const int n = blockIdx.x * 4 + wave;
    if (n >= N) return;
    const int beg = row[n], end = row[n + 1];

    // phase A: per-head max; lane = j*8 + h reads alpha[(base+j)*8 + h] (coalesced)
    float mx = -1e30f;
    for (int base = beg; base < end; base += 8) {
        int idx = base + (lane >> 3);
        float a = (idx < end) ? alpha[(size_t)base * 8 + lane] : -1e30f;
        mx = fmaxf(mx, a);
    }
    mx = fmaxf(mx, __shfl_xor(mx, 8));
    mx = fmaxf(mx, __shfl_xor(mx, 16));
    mx = fmaxf(mx, __shfl_xor(mx, 32));
    const int h2 = lane >> 3;
    float mxB = __shfl(mx, h2);        // max for head h2

    // phase B: p = exp(a - m), dsum, acc
    float dsum = 0.f, acc = 0.f;
    int2 ec = csrp[beg];
    for (int idx = beg; idx < end; ++idx) {
        const int s = ec.y;
        float av = alpha[(size_t)idx * 8 + h2];
        unsigned short vu = vb[(size_t)s * 64 + lane];
        if (idx + 1 < end) ec = csrp[idx + 1];
        float p = __expf(av - mxB);
        dsum += p;
        acc += p * bf2f(vu);
    }
    float outv = acc / (dsum + 1e-16f);

    // fused output projection
    float po[8];
    #pragma unroll
    for (int cp8 = 0; cp8 < 8; cp8++) po[cp8] = outv * Wo[cp8 * 64 + lane];
    #pragma unroll
    for (int m = 1; m < 64; m <<= 1) {
        #pragma unroll
        for (int cp8 = 0; cp8 < 8; cp8++) po[cp8] += __shfl_xor(po[cp8], m);
    }
    if (lane < 8) out[(size_t)n * 8 + lane] = po[lane] + bo[lane];
}

extern "C" void kernel_launch(void* const* d_in, const int* in_sizes, int n_in,
                              void* d_out, int out_size, void* d_ws, size_t ws_size,
                              hipStream_t stream)
{
    const float* x     = (const float*)d_in[0];
    const int*   ei    = (const int*)d_in[1];
    const float* eattr = (const float*)d_in[2];
    const float* tp    = (const float*)d_in[3];
    const float* Wq    = (const float*)d_in[4];
    const float* Wk    = (const float*)d_in[5];
    const float* Wv    = (const float*)d_in[6];
    const float* We    = (const float*)d_in[7];
    const float* compW = (const float*)d_in[8];
    const float* compb = (const float*)d_in[9];
    const float* Wo    = (const float*)d_in[10];
    const float* bo    = (const float*)d_in[11];
    float* out = (float*)d_out;

    const int N  = in_sizes[0] / 128;
    const int E0 = in_sizes[1] / 2;
    const int E  = E0 + N;
    const int NB = (N + 255) / 256;

    float* ws = (float*)d_ws;
    size_t off = 0;
    unsigned short* tpnb = (unsigned short*)(ws + off); off += (size_t)N * 48;   // N*96 ushort
    float* q  = ws + off; off += (size_t)N * 64;
    unsigned short* kb = (unsigned short*)(ws + off); off += (size_t)N * 32;     // N*64 ushort
    unsigned short* vb = (unsigned short*)(ws + off); off += (size_t)N * 32;
    unsigned short* Gb = (unsigned short*)(ws + off); off += (size_t)N * 64;     // N*128 ushort
    float* an = ws + off; off += (size_t)N * 8;
    float* bn = ws + off; off += (size_t)N * 8;
    int* deg    = (int*)(ws + off); off += N;
    int* rowp   = (int*)(ws + off); off += N + 1;
    int* cursor = (int*)(ws + off); off += N;
    int* bsum   = (int*)(ws + off); off += 256;
    int2* csrp  = (int2*)(ws + off); off += (size_t)E * 2;
    int* dstA   = (int*)(ws + off); off += E;
    float* alpha = ws + off; off += (size_t)E * 8;

    hipMemsetAsync(deg, 0, (size_t)N * sizeof(int), stream);

    k_hist<<<(E + 255) / 256, 256, 0, stream>>>(ei, deg, E0, N);
    k_scanA<<<NB, 256, 0, stream>>>(deg, bsum, N);
    k_scanB<<<1, 256, 0, stream>>>(bsum, NB);
    k_scanC<<<NB, 256, 0, stream>>>(deg, bsum, rowp, cursor, N);
    k_scatter<<<(E + 255) / 256, 256, 0, stream>>>(ei, cursor, csrp, dstA, E0, N);

    k_proj<<<(N + 63) / 64, 256, 0, stream>>>(x, Wq, Wk, Wv, compW, compb,
                                              q, kb, vb, an, bn, N);
    k_G<<<((size_t)N * 128 + 255) / 256, 256, 0, stream>>>(kb, We, Gb, N);
    k_tpn<<<(N + 3) / 4, 256, 0, stream>>>(tp, tpnb, N);
    k_logits<<<(E + 31) / 32, 256, 0, stream>>>(csrp, dstA, eattr, tpnb, q, kb, Gb,
                                                an, bn, alpha, E0, E);
    k_agg<<<(N + 3) / 4, 256, 0, stream>>>(csrp, rowp, alpha, vb, Wo, bo, out, N);
}

// Round 7
// 331.026 us; speedup vs baseline: 1.1458x; 1.1458x over previous
//
#include <hip/hip_runtime.h>
#include <math.h>

// N=50000 nodes, E0=800000 edges (+N self loops), IN=128, H=8, C=8 (HC=64), ED=16, T=96

struct __align__(8) US4 { unsigned short x, y, z, w; };

__device__ __forceinline__ unsigned short f2bf(float f) {
    unsigned u = __float_as_uint(f);
    unsigned r = (u + 0x7fffu + ((u >> 16) & 1u)) >> 16;
    return (unsigned short)r;
}
__device__ __forceinline__ float bf2f(unsigned short u) {
    return __uint_as_float(((unsigned)u) << 16);
}
__device__ __forceinline__ float blo(unsigned u) { return __uint_as_float(u << 16); }
__device__ __forceinline__ float bhi(unsigned u) { return __uint_as_float(u & 0xffff0000u); }

// ---------------- node projections: q (f32, pre-scaled 1/sqrt8), k,v (bf16), an,bn (f32) ----
__global__ __launch_bounds__(256) void k_proj(
    const float* __restrict__ x,
    const float* __restrict__ Wq, const float* __restrict__ Wk, const float* __restrict__ Wv,
    const float* __restrict__ compW, const float* __restrict__ compb,
    float* __restrict__ q, unsigned short* __restrict__ kb, unsigned short* __restrict__ vb,
    float* __restrict__ an, float* __restrict__ bn, int N)
{
    __shared__ float xt[64 * 128];
    const int n0 = blockIdx.x * 64;
    const int tid = threadIdx.x;
    for (int i = tid; i < 2048; i += 256) {
        int row = i >> 5, c4 = i & 31;
        int n = n0 + row;
        float4 val = make_float4(0.f, 0.f, 0.f, 0.f);
        if (n < N) val = ((const float4*)(x + (size_t)n * 128))[c4];
        ((float4*)xt)[i] = val;
    }
    __syncthreads();
    if (tid >= 208) return;
    const int sh = tid / 52;          // node quarter (16 nodes)
    const int cq = tid % 52;          // column quad

    const float* wrow; int wstride;
    if (cq < 16)      { wrow = Wq + (size_t)cq * 4 * 128;          wstride = 128; }
    else if (cq < 32) { wrow = Wk + (size_t)(cq - 16) * 4 * 128;   wstride = 128; }
    else if (cq < 48) { wrow = Wv + (size_t)(cq - 32) * 4 * 128;   wstride = 128; }
    else if (cq < 50) { wrow = compW + (size_t)(cq - 48) * 4 * 256;       wstride = 256; }
    else              { wrow = compW + (size_t)(cq - 50) * 4 * 256 + 128; wstride = 256; }

    float acc[16][4];
    #pragma unroll
    for (int i = 0; i < 16; i++)
        #pragma unroll
        for (int j = 0; j < 4; j++) acc[i][j] = 0.f;

    const float4* xt4 = (const float4*)xt;
    for (int k4 = 0; k4 < 32; k4++) {
        float4 w0 = ((const float4*)(wrow + 0 * wstride))[k4];
        float4 w1 = ((const float4*)(wrow + 1 * wstride))[k4];
        float4 w2 = ((const float4*)(wrow + 2 * wstride))[k4];
        float4 w3 = ((const float4*)(wrow + 3 * wstride))[k4];
        #pragma unroll
        for (int nn = 0; nn < 16; nn++) {
            float4 x4 = xt4[(sh * 16 + nn) * 32 + k4];
            acc[nn][0] += x4.x * w0.x + x4.y * w0.y + x4.z * w0.z + x4.w * w0.w;
            acc[nn][1] += x4.x * w1.x + x4.y * w1.y + x4.z * w1.z + x4.w * w1.w;
            acc[nn][2] += x4.x * w2.x + x4.y * w2.y + x4.z * w2.z + x4.w * w2.w;
            acc[nn][3] += x4.x * w3.x + x4.y * w3.y + x4.z * w3.z + x4.w * w3.w;
        }
    }
    #pragma unroll
    for (int nn = 0; nn < 16; nn++) {
        int n = n0 + sh * 16 + nn;
        if (n >= N) continue;
        if (cq < 16) {
            const float qs = 0.35355339059327373f;
            float4 r = make_float4(acc[nn][0] * qs, acc[nn][1] * qs,
                                   acc[nn][2] * qs, acc[nn][3] * qs);
            ((float4*)(q + (size_t)n * 64))[cq] = r;
        } else if (cq < 32) {
            US4 u = { f2bf(acc[nn][0]), f2bf(acc[nn][1]), f2bf(acc[nn][2]), f2bf(acc[nn][3]) };
            ((US4*)(kb + (size_t)n * 64))[cq - 16] = u;
        } else if (cq < 48) {
            US4 u = { f2bf(acc[nn][0]), f2bf(acc[nn][1]), f2bf(acc[nn][2]), f2bf(acc[nn][3]) };
            ((US4*)(vb + (size_t)n * 64))[cq - 32] = u;
        } else if (cq < 50) {
            float4 r = make_float4(acc[nn][0], acc[nn][1], acc[nn][2], acc[nn][3]);
            ((float4*)(an + (size_t)n * 8))[cq - 48] = r;
        } else {
            int c0 = (cq - 50) * 4;
            float4 r = make_float4(acc[nn][0] + compb[c0],     acc[nn][1] + compb[c0 + 1],
                                   acc[nn][2] + compb[c0 + 2], acc[nn][3] + compb[c0 + 3]);
            ((float4*)(bn + (size_t)n * 8))[cq - 50] = r;
        }
    }
}

// ---------------- G precompute: G[s][h][d] = sum_c We[h*8+c][d] * k[s][h*8+c] (bf16) --------
__global__ __launch_bounds__(256) void k_G(
    const unsigned short* __restrict__ kb, const float* __restrict__ We,
    unsigned short* __restrict__ Gb, int N)
{
    __shared__ float WeS[1024];      // We[hc][d], 64x16
    const int tid = threadIdx.x;
    for (int i = tid; i < 1024; i += 256) WeS[i] = We[i];
    __syncthreads();
    int gid = blockIdx.x * 256 + tid;
    if (gid >= N * 128) return;
    int s = gid >> 7, hd = gid & 127, h = hd >> 4, d = hd & 15;
    const US4* kp = (const US4*)(kb + (size_t)s * 64 + h * 8);
    US4 k0 = kp[0], k1 = kp[1];
    const float* w = WeS + (h * 8) * 16 + d;
    float g = bf2f(k0.x) * w[0]   + bf2f(k0.y) * w[16]  + bf2f(k0.z) * w[32]  + bf2f(k0.w) * w[48]
            + bf2f(k1.x) * w[64]  + bf2f(k1.y) * w[80]  + bf2f(k1.z) * w[96]  + bf2f(k1.w) * w[112];
    Gb[(size_t)s * 128 + hd] = f2bf(g);
}

// ---------------- temporal profile normalization (ddof=1) -> bf16, one wave per node ----------
__global__ __launch_bounds__(256) void k_tpn(const float* __restrict__ tp,
                                             unsigned short* __restrict__ tpnb, int N)
{
    int wave = threadIdx.x >> 6;
    int lane = threadIdx.x & 63;
    int n = blockIdx.x * 4 + wave;
    if (n >= N) return;
    const float* row = tp + (size_t)n * 96;
    float v0 = row[lane];
    float v1 = (lane < 32) ? row[64 + lane] : 0.f;
    float s = v0 + v1, ss = v0 * v0 + v1 * v1;
    #pragma unroll
    for (int m = 1; m < 64; m <<= 1) { s += __shfl_xor(s, m); ss += __shfl_xor(ss, m); }
    float mean = s * (1.f / 96.f);
    float var = (ss - 96.f * mean * mean) * (1.f / 95.f);
    var = fmaxf(var, 0.f);
    float inv = 1.f / (sqrtf(var) + 1e-8f);
    unsigned short* orow = tpnb + (size_t)n * 96;
    orow[lane] = f2bf((v0 - mean) * inv);
    if (lane < 32) orow[64 + lane] = f2bf((v1 - mean) * inv);
}

// ---------------- CSR build: histogram(+rank) / 3-stage scan / atomic-free scatter ----------
__global__ __launch_bounds__(256) void k_hist(const int* __restrict__ ei,
                                              int* __restrict__ deg,
                                              int* __restrict__ rnk, int E0, int N)
{
    int e = blockIdx.x * 256 + threadIdx.x;
    int E = E0 + N;
    if (e >= E) return;
    int dst = (e < E0) ? ei[E0 + e] : (e - E0);
    rnk[e] = atomicAdd(&deg[dst], 1);
}

__global__ __launch_bounds__(256) void k_scanA(const int* __restrict__ deg,
                                               int* __restrict__ bsum, int N)
{
    __shared__ int sm[256];
    int i = blockIdx.x * 256 + threadIdx.x;
    sm[threadIdx.x] = (i < N) ? deg[i] : 0;
    __syncthreads();
    for (int off = 128; off > 0; off >>= 1) {
        if (threadIdx.x < off) sm[threadIdx.x] += sm[threadIdx.x + off];
        __syncthreads();
    }
    if (threadIdx.x == 0) bsum[blockIdx.x] = sm[0];
}

__global__ __launch_bounds__(256) void k_scanB(int* __restrict__ bsum, int NB)
{
    __shared__ int sm[256];
    int t = threadIdx.x;
    sm[t] = (t < NB) ? bsum[t] : 0;
    __syncthreads();
    for (int off = 1; off < 256; off <<= 1) {
        int v = (t >= off) ? sm[t - off] : 0;
        __syncthreads();
        sm[t] += v;
        __syncthreads();
    }
    if (t < NB) bsum[t] = (t == 0) ? 0 : sm[t - 1];
}

__global__ __launch_bounds__(256) void k_scanC(const int* __restrict__ deg,
                                               const int* __restrict__ bsum,
                                               int* __restrict__ row, int N)
{
    __shared__ int sm[256];
    int b = blockIdx.x, t = threadIdx.x, i = b * 256 + t;
    int v = (i < N) ? deg[i] : 0;
    sm[t] = v;
    __syncthreads();
    for (int off = 1; off < 256; off <<= 1) {
        int u = (t >= off) ? sm[t - off] : 0;
        __syncthreads();
        sm[t] += u;
        __syncthreads();
    }
    int excl = bsum[b] + sm[t] - v;
    if (i < N) {
        row[i] = excl;
        if (i == N - 1) row[N] = excl + v;
    }
}

__global__ __launch_bounds__(256) void k_scatter(const int* __restrict__ ei,
                                                 const int* __restrict__ row,
                                                 const int* __restrict__ rnk,
                                                 int4* __restrict__ csrd, int E0, int N)
{
    int e = blockIdx.x * 256 + threadIdx.x;
    int E = E0 + N;
    if (e >= E) return;
    int src, dst;
    if (e < E0) { src = ei[e]; dst = ei[E0 + e]; }
    else        { src = e - E0; dst = src; }
    int pos = row[dst] + rnk[e];
    csrd[pos] = make_int4(e, src, dst, 0);
}

// ---------------- per-edge logit ----------------
__device__ __forceinline__ float edge_logit(
    int e, int s, int d, int h,
    const float* __restrict__ eattr, const unsigned short* __restrict__ tpnb,
    const float* __restrict__ q, const unsigned short* __restrict__ kb,
    const unsigned short* __restrict__ Gb,
    const float* __restrict__ an, const float* __restrict__ bn, int E0)
{
    // qk (q pre-scaled by 1/sqrt8)
    const float4* qp = (const float4*)(q + (size_t)d * 64 + h * 8);
    float4 q0 = qp[0], q1 = qp[1];
    const US4* kp = (const US4*)(kb + (size_t)s * 64 + h * 8);
    US4 k0 = kp[0], k1 = kp[1];
    float qk = q0.x * bf2f(k0.x) + q0.y * bf2f(k0.y) + q0.z * bf2f(k0.z) + q0.w * bf2f(k0.w)
             + q1.x * bf2f(k1.x) + q1.y * bf2f(k1.y) + q1.z * bf2f(k1.z) + q1.w * bf2f(k1.w);

    // efk = sum_d ea[d] * G[s][h][d]; self-loop => ea = ones (branch-free select)
    const uint4* gp = (const uint4*)(Gb + (size_t)s * 128 + h * 16);
    uint4 g0 = gp[0], g1 = gp[1];
    int ec = (e < E0) ? e : 0;
    const float4* ep = (const float4*)(eattr + (size_t)ec * 16);
    float4 e0 = ep[0], e1 = ep[1], e2 = ep[2], e3 = ep[3];
    if (e >= E0) {
        e0 = make_float4(1.f, 1.f, 1.f, 1.f); e1 = e0; e2 = e0; e3 = e0;
    }
    float efk = e0.x * blo(g0.x) + e0.y * bhi(g0.x) + e0.z * blo(g0.y) + e0.w * bhi(g0.y)
              + e1.x * blo(g0.z) + e1.y * bhi(g0.z) + e1.z * blo(g0.w) + e1.w * bhi(g0.w)
              + e2.x * blo(g1.x) + e2.y * bhi(g1.x) + e2.z * blo(g1.y) + e2.w * bhi(g1.y)
              + e3.x * blo(g1.z) + e3.y * bhi(g1.z) + e3.z * blo(g1.w) + e3.w * bhi(g1.w);

    // tanh term (bn already includes comp_b)
    float tv = an[(size_t)s * 8 + h] + bn[(size_t)d * 8 + h];
    float ex = __expf(2.f * tv);
    float t = 1.f - 2.f / (ex + 1.f);

    // correlation partial: lane h covers t-range [12h, 12h+12)
    const uint2* tsp = (const uint2*)(tpnb + (size_t)s * 96 + h * 12);
    const uint2* tdp = (const uint2*)(tpnb + (size_t)d * 96 + h * 12);
    float pc = 0.f;
    #pragma unroll
    for (int i = 0; i < 3; i++) {
        uint2 us = tsp[i], ud = tdp[i];
        pc += blo(us.x) * blo(ud.x) + bhi(us.x) * bhi(ud.x)
            + blo(us.y) * blo(ud.y) + bhi(us.y) * bhi(ud.y);
    }
    float cv = pc * (-0.25f / 96.f) + t * (-0.25f / 8.f);
    cv += __shfl_xor(cv, 1); cv += __shfl_xor(cv, 2); cv += __shfl_xor(cv, 4);

    float a = qk + efk + cv;
    return fmaxf(a, 0.2f * a);                     // leaky relu
}

// ---------------- edge-parallel logits (CSR order): 2 edges per thread-group ----------
__global__ __launch_bounds__(256) void k_logits(
    const int4* __restrict__ csrd,
    const float* __restrict__ eattr,
    const unsigned short* __restrict__ tpnb, const float* __restrict__ q,
    const unsigned short* __restrict__ kb, const unsigned short* __restrict__ Gb,
    const float* __restrict__ an, const float* __restrict__ bn,
    float* __restrict__ alpha, int E0, int E)
{
    const int tid = threadIdx.x;
    const int h = tid & 7;
    const int t = tid >> 3;                  // 0..31
    const int ia = blockIdx.x * 64 + t;
    const int ib = ia + 32;

    if (ia < E) {
        int4 ca = csrd[ia];
        if (ib < E) {
            int4 cb = csrd[ib];
            float aa = edge_logit(ca.x, ca.y, ca.z, h, eattr, tpnb, q, kb, Gb, an, bn, E0);
            float ab = edge_logit(cb.x, cb.y, cb.z, h, eattr, tpnb, q, kb, Gb, an, bn, E0);
            alpha[(size_t)ia * 8 + h] = aa;
            alpha[(size_t)ib * 8 + h] = ab;
        } else {
            float aa = edge_logit(ca.x, ca.y, ca.z, h, eattr, tpnb, q, kb, Gb, an, bn, E0);
            alpha[(size_t)ia * 8 + h] = aa;
        }
    }
}

// ---------------- per-node: softmax over CSR-ordered alpha + V agg + Wo ----------------
// one wave per node; phase B: 2 edge-slots x 32 channel-pair lanes, SW-pipelined
__global__ __launch_bounds__(256) void k_agg(
    const int4* __restrict__ csrd, const int* __restrict__ row,
    const float* __restrict__ alpha, const unsigned short* __restrict__ vb,
    const float* __restrict__ Wo, const float* __restrict__ bo,
    float* __restrict__ out, int N)
{
    const int tid = threadIdx.x;
    const int wave = tid >> 6, lane = tid & 63;
    const int n = blockIdx.x * 4 + wave;
    if (n >= N) return;
    const int beg = row[n], end = row[n + 1];

    // phase A: per-head max; lane = j*8 + hh reads alpha[(base+j)*8 + hh] (coalesced)
    float mx = -1e30f;
    for (int base = beg; base < end; base += 8) {
        int idx = base + (lane >> 3);
        float a = (idx < end) ? alpha[(size_t)base * 8 + lane] : -1e30f;
        mx = fmaxf(mx, a);
    }
    mx = fmaxf(mx, __shfl_xor(mx, 8));
    mx = fmaxf(mx, __shfl_xor(mx, 16));
    mx = fmaxf(mx, __shfl_xor(mx, 32));

    // phase B layout: sl = edge slot (0/1), cp = channel pair, h = head of channels 2cp,2cp+1
    const int sl = lane >> 5;
    const int cp = lane & 31;
    const int h = cp >> 2;
    float mxH = __shfl(mx, h);       // lane h holds head h's max

    float dsum = 0.f, accx = 0.f, accy = 0.f;
    const int i0 = beg + sl;
    int sv0 = 0, sv1 = 0; float av0 = 0.f, av1 = 0.f; unsigned vu0 = 0;
    if (i0 < end) {
        sv0 = csrd[i0].y;
        av0 = alpha[(size_t)i0 * 8 + h];
        vu0 = *(const unsigned*)(vb + (size_t)sv0 * 64 + 2 * cp);
    }
    if (i0 + 2 < end) {
        sv1 = csrd[i0 + 2].y;
        av1 = alpha[(size_t)(i0 + 2) * 8 + h];
    }
    for (int i = i0; i < end; i += 2) {
        unsigned vu1 = 0;
        if (i + 2 < end) vu1 = *(const unsigned*)(vb + (size_t)sv1 * 64 + 2 * cp);
        int sv2 = 0; float av2 = 0.f;
        if (i + 4 < end) {
            sv2 = csrd[i + 4].y;
            av2 = alpha[(size_t)(i + 4) * 8 + h];
        }
        float p = __expf(av0 - mxH);
        dsum += p;
        accx += p * blo(vu0);
        accy += p * bhi(vu0);
        sv0 = sv1; av0 = av1; vu0 = vu1;
        sv1 = sv2; av1 = av2;
    }
    // merge slots
    accx += __shfl_xor(accx, 32);
    accy += __shfl_xor(accy, 32);
    dsum += __shfl_xor(dsum, 32);
    float inv = 1.f / (dsum + 1e-16f);
    float o0 = accx * inv, o1 = accy * inv;

    // fused output projection: lane holds channels 2cp, 2cp+1
    float po[8];
    #pragma unroll
    for (int cp8 = 0; cp8 < 8; cp8++) {
        float2 w = ((const float2*)(Wo + cp8 * 64))[cp];
        po[cp8] = o0 * w.x + o1 * w.y;
    }
    #pragma unroll
    for (int m = 1; m < 32; m <<= 1) {
        #pragma unroll
        for (int cp8 = 0; cp8 < 8; cp8++) po[cp8] += __shfl_xor(po[cp8], m);
    }
    if (lane < 8) out[(size_t)n * 8 + lane] = po[lane] + bo[lane];
}

extern "C" void kernel_launch(void* const* d_in, const int* in_sizes, int n_in,
                              void* d_out, int out_size, void* d_ws, size_t ws_size,
                              hipStream_t stream)
{
    const float* x     = (const float*)d_in[0];
    const int*   ei    = (const int*)d_in[1];
    const float* eattr = (const float*)d_in[2];
    const float* tp    = (const float*)d_in[3];
    const float* Wq    = (const float*)d_in[4];
    const float* Wk    = (const float*)d_in[5];
    const float* Wv    = (const float*)d_in[6];
    const float* We    = (const float*)d_in[7];
    const float* compW = (const float*)d_in[8];
    const float* compb = (const float*)d_in[9];
    const float* Wo    = (const float*)d_in[10];
    const float* bo    = (const float*)d_in[11];
    float* out = (float*)d_out;

    const int N  = in_sizes[0] / 128;
    const int E0 = in_sizes[1] / 2;
    const int E  = E0 + N;
    const int NB = (N + 255) / 256;

    float* ws = (float*)d_ws;
    size_t off = 0;
    unsigned short* tpnb = (unsigned short*)(ws + off); off += (size_t)N * 48;   // N*96 ushort
    float* q  = ws + off; off += (size_t)N * 64;
    unsigned short* kb = (unsigned short*)(ws + off); off += (size_t)N * 32;     // N*64 ushort
    unsigned short* vb = (unsigned short*)(ws + off); off += (size_t)N * 32;
    unsigned short* Gb = (unsigned short*)(ws + off); off += (size_t)N * 64;     // N*128 ushort
    float* an = ws + off; off += (size_t)N * 8;
    float* bn = ws + off; off += (size_t)N * 8;
    int* deg    = (int*)(ws + off); off += N;
    int* rowp   = (int*)(ws + off); off += N + 1;
    int* bsum   = (int*)(ws + off); off += 256;
    int4* csrd  = (int4*)(ws + off); off += (size_t)E * 4;
    float* alpha = ws + off; off += (size_t)E * 8;
    int* rnk = (int*)alpha;          // overlay: rnk used before alpha is written

    hipMemsetAsync(deg, 0, (size_t)N * sizeof(int), stream);

    k_hist<<<(E + 255) / 256, 256, 0, stream>>>(ei, deg, rnk, E0, N);
    k_scanA<<<NB, 256, 0, stream>>>(deg, bsum, N);
    k_scanB<<<1, 256, 0, stream>>>(bsum, NB);
    k_scanC<<<NB, 256, 0, stream>>>(deg, bsum, rowp, N);
    k_scatter<<<(E + 255) / 256, 256, 0, stream>>>(ei, rowp, rnk, csrd, E0, N);

    k_proj<<<(N + 63) / 64, 256, 0, stream>>>(x, Wq, Wk, Wv, compW, compb,
                                              q, kb, vb, an, bn, N);
    k_G<<<((size_t)N * 128 + 255) / 256, 256, 0, stream>>>(kb, We, Gb, N);
    k_tpn<<<(N + 3) / 4, 256, 0, stream>>>(tp, tpnb, N);
    k_logits<<<(E + 63) / 64, 256, 0, stream>>>(csrd, eattr, tpnb, q, kb, Gb,
                                                an, bn, alpha, E0, E);
    k_agg<<<(N + 3) / 4, 256, 0, stream>>>(csrd, rowp, alpha, vb, Wo, bo, out, N);
}

// Round 8
// 257.156 us; speedup vs baseline: 1.4749x; 1.2873x over previous
//
#include <hip/hip_runtime.h>
#include <math.h>

// N=50000 nodes, E0=800000 edges (+N self loops), IN=128, H=8, C=8 (HC=64), ED=16, T=96
// Node-side outputs are one MFMA GEMM: x[N][128] @ B[128][336] where
// cols 0-63=q (pre-scaled), 64-127=k, 128-191=v, 192-199=an, 200-207=bn(+comp_b),
// 208-335=G[h*16+d] with Wg = Wk^T-composed We (G = k@blockdiag(We) = x@(Wk^T Wg)).

struct __align__(8) US4 { unsigned short x, y, z, w; };

typedef __attribute__((ext_vector_type(8))) short bf16x8;
typedef __attribute__((ext_vector_type(4))) float f32x4;

__device__ __forceinline__ unsigned short f2bf(float f) {
    unsigned u = __float_as_uint(f);
    unsigned r = (u + 0x7fffu + ((u >> 16) & 1u)) >> 16;
    return (unsigned short)r;
}
__device__ __forceinline__ float bf2f(unsigned short u) {
    return __uint_as_float(((unsigned)u) << 16);
}
__device__ __forceinline__ float blo(unsigned u) { return __uint_as_float(u << 16); }
__device__ __forceinline__ float bhi(unsigned u) { return __uint_as_float(u & 0xffff0000u); }

// ---------------- x -> bf16 ----------------
__global__ __launch_bounds__(256) void k_xcvt(const float* __restrict__ x,
                                              unsigned short* __restrict__ xb, int total4)
{
    int i = blockIdx.x * 256 + threadIdx.x;
    if (i >= total4) return;
    float4 v = ((const float4*)x)[i];
    US4 u = { f2bf(v.x), f2bf(v.y), f2bf(v.z), f2bf(v.w) };
    ((US4*)xb)[i] = u;
}

// ---------------- pack B fragments: Bp[((t*4+s)*64+lane)*8+i] ----------------
// col = t*16 + (lane&15); k = s*32 + (lane>>4)*8 + i
__global__ __launch_bounds__(256) void k_bpack(
    const float* __restrict__ Wq, const float* __restrict__ Wk, const float* __restrict__ Wv,
    const float* __restrict__ compW, const float* __restrict__ We,
    unsigned short* __restrict__ Bp)
{
    int gid = blockIdx.x * 256 + threadIdx.x;
    if (gid >= 21 * 2048) return;                 // 43008
    int i = gid & 7, lane = (gid >> 3) & 63, s = (gid >> 9) & 3, t = gid >> 11;
    int col = t * 16 + (lane & 15);
    int k = s * 32 + ((lane >> 4) << 3) + i;
    float v;
    if (col < 64)        v = Wq[col * 128 + k];
    else if (col < 128)  v = Wk[(col - 64) * 128 + k];
    else if (col < 192)  v = Wv[(col - 128) * 128 + k];
    else if (col < 200)  v = compW[(col - 192) * 256 + k];
    else if (col < 208)  v = compW[(col - 200) * 256 + 128 + k];
    else {
        int hd = col - 208, h = hd >> 4, d = hd & 15;
        v = 0.f;
        #pragma unroll
        for (int c = 0; c < 8; c++)
            v += Wk[(h * 8 + c) * 128 + k] * We[(h * 8 + c) * 16 + d];
    }
    Bp[gid] = f2bf(v);
}

// ---------------- MFMA projection GEMM: 64 rows/block, wave = 16-row subtile ----------------
__global__ __launch_bounds__(256) void k_gemm(
    const unsigned short* __restrict__ xb, const unsigned short* __restrict__ Bp,
    const float* __restrict__ compb,
    float* __restrict__ q, unsigned short* __restrict__ kb, unsigned short* __restrict__ vb,
    float* __restrict__ an, float* __restrict__ bn, unsigned short* __restrict__ Gb, int N)
{
    const int tid = threadIdx.x, w = tid >> 6, lane = tid & 63;
    const int half = lane >> 4;                   // 0..3
    const int c0 = lane & 15;
    int row_a = blockIdx.x * 64 + w * 16 + c0;
    int ra = min(row_a, N - 1);
    bf16x8 a0 = *(const bf16x8*)(xb + (size_t)ra * 128 +  0 + half * 8);
    bf16x8 a1 = *(const bf16x8*)(xb + (size_t)ra * 128 + 32 + half * 8);
    bf16x8 a2 = *(const bf16x8*)(xb + (size_t)ra * 128 + 64 + half * 8);
    bf16x8 a3 = *(const bf16x8*)(xb + (size_t)ra * 128 + 96 + half * 8);
    const int rbase = blockIdx.x * 64 + w * 16 + half * 4;
    const float cbv = compb[c0 & 7];

    for (int t = 0; t < 21; t++) {
        f32x4 acc = {0.f, 0.f, 0.f, 0.f};
        const bf16x8* bp = (const bf16x8*)(Bp + (size_t)((t * 4) * 64 + lane) * 8);
        acc = __builtin_amdgcn_mfma_f32_16x16x32_bf16(a0, bp[0],   acc, 0, 0, 0);
        acc = __builtin_amdgcn_mfma_f32_16x16x32_bf16(a1, bp[64],  acc, 0, 0, 0);
        acc = __builtin_amdgcn_mfma_f32_16x16x32_bf16(a2, bp[128], acc, 0, 0, 0);
        acc = __builtin_amdgcn_mfma_f32_16x16x32_bf16(a3, bp[192], acc, 0, 0, 0);
        #pragma unroll
        for (int r = 0; r < 4; r++) {
            int rr = rbase + r;
            if (rr >= N) continue;
            float vr = acc[r];
            if (t < 4)        q[(size_t)rr * 64 + t * 16 + c0] = vr * 0.35355339059327373f;
            else if (t < 8)   kb[(size_t)rr * 64 + (t - 4) * 16 + c0] = f2bf(vr);
            else if (t < 12)  vb[(size_t)rr * 64 + (t - 8) * 16 + c0] = f2bf(vr);
            else if (t == 12) {
                if (c0 < 8) an[(size_t)rr * 8 + c0] = vr;
                else        bn[(size_t)rr * 8 + (c0 - 8)] = vr + cbv;
            }
            else              Gb[(size_t)rr * 128 + (t - 13) * 16 + c0] = f2bf(vr);
        }
    }
}

// ---------------- temporal profile normalization (ddof=1) -> bf16, one wave per node ----------
__global__ __launch_bounds__(256) void k_tpn(const float* __restrict__ tp,
                                             unsigned short* __restrict__ tpnb, int N)
{
    int wave = threadIdx.x >> 6;
    int lane = threadIdx.x & 63;
    int n = blockIdx.x * 4 + wave;
    if (n >= N) return;
    const float* row = tp + (size_t)n * 96;
    float v0 = row[lane];
    float v1 = (lane < 32) ? row[64 + lane] : 0.f;
    float s = v0 + v1, ss = v0 * v0 + v1 * v1;
    #pragma unroll
    for (int m = 1; m < 64; m <<= 1) { s += __shfl_xor(s, m); ss += __shfl_xor(ss, m); }
    float mean = s * (1.f / 96.f);
    float var = (ss - 96.f * mean * mean) * (1.f / 95.f);
    var = fmaxf(var, 0.f);
    float inv = 1.f / (sqrtf(var) + 1e-8f);
    unsigned short* orow = tpnb + (size_t)n * 96;
    orow[lane] = f2bf((v0 - mean) * inv);
    if (lane < 32) orow[64 + lane] = f2bf((v1 - mean) * inv);
}

// ---------------- CSR build: histogram(+rank) / 3-stage scan / atomic-free scatter ----------
__global__ __launch_bounds__(256) void k_hist(const int* __restrict__ ei,
                                              int* __restrict__ deg,
                                              int* __restrict__ rnk, int E0, int N)
{
    int e = blockIdx.x * 256 + threadIdx.x;
    int E = E0 + N;
    if (e >= E) return;
    int dst = (e < E0) ? ei[E0 + e] : (e - E0);
    rnk[e] = atomicAdd(&deg[dst], 1);
}

__global__ __launch_bounds__(256) void k_scanA(const int* __restrict__ deg,
                                               int* __restrict__ bsum, int N)
{
    __shared__ int sm[256];
    int i = blockIdx.x * 256 + threadIdx.x;
    sm[threadIdx.x] = (i < N) ? deg[i] : 0;
    __syncthreads();
    for (int off = 128; off > 0; off >>= 1) {
        if (threadIdx.x < off) sm[threadIdx.x] += sm[threadIdx.x + off];
        __syncthreads();
    }
    if (threadIdx.x == 0) bsum[blockIdx.x] = sm[0];
}

__global__ __launch_bounds__(256) void k_scanB(int* __restrict__ bsum, int NB)
{
    __shared__ int sm[256];
    int t = threadIdx.x;
    sm[t] = (t < NB) ? bsum[t] : 0;
    __syncthreads();
    for (int off = 1; off < 256; off <<= 1) {
        int v = (t >= off) ? sm[t - off] : 0;
        __syncthreads();
        sm[t] += v;
        __syncthreads();
    }
    if (t < NB) bsum[t] = (t == 0) ? 0 : sm[t - 1];
}

__global__ __launch_bounds__(256) void k_scanC(const int* __restrict__ deg,
                                               const int* __restrict__ bsum,
                                               int* __restrict__ row, int N)
{
    __shared__ int sm[256];
    int b = blockIdx.x, t = threadIdx.x, i = b * 256 + t;
    int v = (i < N) ? deg[i] : 0;
    sm[t] = v;
    __syncthreads();
    for (int off = 1; off < 256; off <<= 1) {
        int u = (t >= off) ? sm[t - off] : 0;
        __syncthreads();
        sm[t] += u;
        __syncthreads();
    }
    int excl = bsum[b] + sm[t] - v;
    if (i < N) {
        row[i] = excl;
        if (i == N - 1) row[N] = excl + v;
    }
}

__global__ __launch_bounds__(256) void k_scatter(const int* __restrict__ ei,
                                                 const int* __restrict__ row,
                                                 const int* __restrict__ rnk,
                                                 int4* __restrict__ csrd, int E0, int N)
{
    int e = blockIdx.x * 256 + threadIdx.x;
    int E = E0 + N;
    if (e >= E) return;
    int src, dst;
    if (e < E0) { src = ei[e]; dst = ei[E0 + e]; }
    else        { src = e - E0; dst = src; }
    int pos = row[dst] + rnk[e];
    csrd[pos] = make_int4(e, src, dst, 0);
}

// ---------------- per-edge logit ----------------
__device__ __forceinline__ float edge_logit(
    int e, int s, int d, int h,
    const float* __restrict__ eattr, const unsigned short* __restrict__ tpnb,
    const float* __restrict__ q, const unsigned short* __restrict__ kb,
    const unsigned short* __restrict__ Gb,
    const float* __restrict__ an, const float* __restrict__ bn, int E0)
{
    // qk (q pre-scaled by 1/sqrt8)
    const float4* qp = (const float4*)(q + (size_t)d * 64 + h * 8);
    float4 q0 = qp[0], q1 = qp[1];
    const US4* kp = (const US4*)(kb + (size_t)s * 64 + h * 8);
    US4 k0 = kp[0], k1 = kp[1];
    float qk = q0.x * bf2f(k0.x) + q0.y * bf2f(k0.y) + q0.z * bf2f(k0.z) + q0.w * bf2f(k0.w)
             + q1.x * bf2f(k1.x) + q1.y * bf2f(k1.y) + q1.z * bf2f(k1.z) + q1.w * bf2f(k1.w);

    // efk = sum_d ea[d] * G[s][h][d]; self-loop => ea = ones (branch-free select)
    const uint4* gp = (const uint4*)(Gb + (size_t)s * 128 + h * 16);
    uint4 g0 = gp[0], g1 = gp[1];
    int ec = (e < E0) ? e : 0;
    const float4* ep = (const float4*)(eattr + (size_t)ec * 16);
    float4 e0 = ep[0], e1 = ep[1], e2 = ep[2], e3 = ep[3];
    if (e >= E0) {
        e0 = make_float4(1.f, 1.f, 1.f, 1.f); e1 = e0; e2 = e0; e3 = e0;
    }
    float efk = e0.x * blo(g0.x) + e0.y * bhi(g0.x) + e0.z * blo(g0.y) + e0.w * bhi(g0.y)
              + e1.x * blo(g0.z) + e1.y * bhi(g0.z) + e1.z * blo(g0.w) + e1.w * bhi(g0.w)
              + e2.x * blo(g1.x) + e2.y * bhi(g1.x) + e2.z * blo(g1.y) + e2.w * bhi(g1.y)
              + e3.x * blo(g1.z) + e3.y * bhi(g1.z) + e3.z * blo(g1.w) + e3.w * bhi(g1.w);

    // tanh term (bn already includes comp_b)
    float tv = an[(size_t)s * 8 + h] + bn[(size_t)d * 8 + h];
    float ex = __expf(2.f * tv);
    float t = 1.f - 2.f / (ex + 1.f);

    // correlation partial: lane h covers t-range [12h, 12h+12)
    const uint2* tsp = (const uint2*)(tpnb + (size_t)s * 96 + h * 12);
    const uint2* tdp = (const uint2*)(tpnb + (size_t)d * 96 + h * 12);
    float pc = 0.f;
    #pragma unroll
    for (int i = 0; i < 3; i++) {
        uint2 us = tsp[i], ud = tdp[i];
        pc += blo(us.x) * blo(ud.x) + bhi(us.x) * bhi(ud.x)
            + blo(us.y) * blo(ud.y) + bhi(us.y) * bhi(ud.y);
    }
    float cv = pc * (-0.25f / 96.f) + t * (-0.25f / 8.f);
    cv += __shfl_xor(cv, 1); cv += __shfl_xor(cv, 2); cv += __shfl_xor(cv, 4);

    float a = qk + efk + cv;
    return fmaxf(a, 0.2f * a);                     // leaky relu
}

// ---------------- edge-parallel logits (CSR order): 2 edges per thread-group ----------
__global__ __launch_bounds__(256) void k_logits(
    const int4* __restrict__ csrd,
    const float* __restrict__ eattr,
    const unsigned short* __restrict__ tpnb, const float* __restrict__ q,
    const unsigned short* __restrict__ kb, const unsigned short* __restrict__ Gb,
    const float* __restrict__ an, const float* __restrict__ bn,
    float* __restrict__ alpha, int E0, int E)
{
    const int tid = threadIdx.x;
    const int h = tid & 7;
    const int t = tid >> 3;                  // 0..31
    const int ia = blockIdx.x * 64 + t;
    const int ib = ia + 32;

    if (ia < E) {
        int4 ca = csrd[ia];
        if (ib < E) {
            int4 cb = csrd[ib];
            float aa = edge_logit(ca.x, ca.y, ca.z, h, eattr, tpnb, q, kb, Gb, an, bn, E0);
            float ab = edge_logit(cb.x, cb.y, cb.z, h, eattr, tpnb, q, kb, Gb, an, bn, E0);
            alpha[(size_t)ia * 8 + h] = aa;
            alpha[(size_t)ib * 8 + h] = ab;
        } else {
            float aa = edge_logit(ca.x, ca.y, ca.z, h, eattr, tpnb, q, kb, Gb, an, bn, E0);
            alpha[(size_t)ia * 8 + h] = aa;
        }
    }
}

// ---------------- per-node: softmax over CSR-ordered alpha + V agg + Wo ----------------
// one wave per node; phase B: 2 edge-slots x 32 channel-pair lanes, SW-pipelined
__global__ __launch_bounds__(256) void k_agg(
    const int4* __restrict__ csrd, const int* __restrict__ row,
    const float* __restrict__ alpha, const unsigned short* __restrict__ vb,
    const float* __restrict__ Wo, const float* __restrict__ bo,
    float* __restrict__ out, int N)
{
    const int tid = threadIdx.x;
    const int wave = tid >> 6, lane = tid & 63;
    const int n = blockIdx.x * 4 + wave;
    if (n >= N) return;
    const int beg = row[n], end = row[n + 1];

    // phase A: per-head max; lane = j*8 + hh reads alpha[(base+j)*8 + hh] (coalesced)
    float mx = -1e30f;
    for (int base = beg; base < end; base += 8) {
        int idx = base + (lane >> 3);
        float a = (idx < end) ? alpha[(size_t)base * 8 + lane] : -1e30f;
        mx = fmaxf(mx, a);
    }
    mx = fmaxf(mx, __shfl_xor(mx, 8));
    mx = fmaxf(mx, __shfl_xor(mx, 16));
    mx = fmaxf(mx, __shfl_xor(mx, 32));

    // phase B layout: sl = edge slot (0/1), cp = channel pair, h = head of channels 2cp,2cp+1
    const int sl = lane >> 5;
    const int cp = lane & 31;
    const int h = cp >> 2;
    float mxH = __shfl(mx, h);       // lane h holds head h's max

    float dsum = 0.f, accx = 0.f, accy = 0.f;
    const int i0 = beg + sl;
    int sv0 = 0, sv1 = 0; float av0 = 0.f, av1 = 0.f; unsigned vu0 = 0;
    if (i0 < end) {
        sv0 = csrd[i0].y;
        av0 = alpha[(size_t)i0 * 8 + h];
        vu0 = *(const unsigned*)(vb + (size_t)sv0 * 64 + 2 * cp);
    }
    if (i0 + 2 < end) {
        sv1 = csrd[i0 + 2].y;
        av1 = alpha[(size_t)(i0 + 2) * 8 + h];
    }
    for (int i = i0; i < end; i += 2) {
        unsigned vu1 = 0;
        if (i + 2 < end) vu1 = *(const unsigned*)(vb + (size_t)sv1 * 64 + 2 * cp);
        int sv2 = 0; float av2 = 0.f;
        if (i + 4 < end) {
            sv2 = csrd[i + 4].y;
            av2 = alpha[(size_t)(i + 4) * 8 + h];
        }
        float p = __expf(av0 - mxH);
        dsum += p;
        accx += p * blo(vu0);
        accy += p * bhi(vu0);
        sv0 = sv1; av0 = av1; vu0 = vu1;
        sv1 = sv2; av1 = av2;
    }
    // merge slots
    accx += __shfl_xor(accx, 32);
    accy += __shfl_xor(accy, 32);
    dsum += __shfl_xor(dsum, 32);
    float inv = 1.f / (dsum + 1e-16f);
    float o0 = accx * inv, o1 = accy * inv;

    // fused output projection: lane holds channels 2cp, 2cp+1
    float po[8];
    #pragma unroll
    for (int cp8 = 0; cp8 < 8; cp8++) {
        float2 w = ((const float2*)(Wo + cp8 * 64))[cp];
        po[cp8] = o0 * w.x + o1 * w.y;
    }
    #pragma unroll
    for (int m = 1; m < 32; m <<= 1) {
        #pragma unroll
        for (int cp8 = 0; cp8 < 8; cp8++) po[cp8] += __shfl_xor(po[cp8], m);
    }
    if (lane < 8) out[(size_t)n * 8 + lane] = po[lane] + bo[lane];
}

extern "C" void kernel_launch(void* const* d_in, const int* in_sizes, int n_in,
                              void* d_out, int out_size, void* d_ws, size_t ws_size,
                              hipStream_t stream)
{
    const float* x     = (const float*)d_in[0];
    const int*   ei    = (const int*)d_in[1];
    const float* eattr = (const float*)d_in[2];
    const float* tp    = (const float*)d_in[3];
    const float* Wq    = (const float*)d_in[4];
    const float* Wk    = (const float*)d_in[5];
    const float* Wv    = (const float*)d_in[6];
    const float* We    = (const float*)d_in[7];
    const float* compW = (const float*)d_in[8];
    const float* compb = (const float*)d_in[9];
    const float* Wo    = (const float*)d_in[10];
    const float* bo    = (const float*)d_in[11];
    float* out = (float*)d_out;

    const int N  = in_sizes[0] / 128;
    const int E0 = in_sizes[1] / 2;
    const int E  = E0 + N;
    const int NB = (N + 255) / 256;

    float* ws = (float*)d_ws;
    size_t off = 0;
    unsigned short* tpnb = (unsigned short*)(ws + off); off += (size_t)N * 48;   // N*96 ushort
    float* q  = ws + off; off += (size_t)N * 64;
    unsigned short* kb = (unsigned short*)(ws + off); off += (size_t)N * 32;     // N*64 ushort
    unsigned short* vb = (unsigned short*)(ws + off); off += (size_t)N * 32;
    unsigned short* Gb = (unsigned short*)(ws + off); off += (size_t)N * 64;     // N*128 ushort
    float* an = ws + off; off += (size_t)N * 8;
    float* bn = ws + off; off += (size_t)N * 8;
    int* deg    = (int*)(ws + off); off += N;
    int* bsum   = (int*)(ws + off); off += 256;
    int* rowp   = (int*)(ws + off); off += N + 4;                                // pad for alignment
    unsigned short* Bp = (unsigned short*)(ws + off); off += 21504 / 2 * 2;      // 43008 ushort = 21504 f
    off += 21504 - 21504 / 2 * 2;                                                // keep exact
    int4* csrd  = (int4*)(ws + off); off += (size_t)E * 4;
    float* alpha = ws + off; off += (size_t)E * 8;
    int* rnk = (int*)alpha;                                   // overlay: used before alpha
    unsigned short* xb = (unsigned short*)(alpha + E);        // overlay: N*128 ushort, dead before alpha

    hipMemsetAsync(deg, 0, (size_t)N * sizeof(int), stream);

    k_hist<<<(E + 255) / 256, 256, 0, stream>>>(ei, deg, rnk, E0, N);
    k_scanA<<<NB, 256, 0, stream>>>(deg, bsum, N);
    k_scanB<<<1, 256, 0, stream>>>(bsum, NB);
    k_scanC<<<NB, 256, 0, stream>>>(deg, bsum, rowp, N);
    k_scatter<<<(E + 255) / 256, 256, 0, stream>>>(ei, rowp, rnk, csrd, E0, N);

    k_xcvt<<<((size_t)N * 32 + 255) / 256, 256, 0, stream>>>(x, xb, N * 32);
    k_bpack<<<(21 * 2048 + 255) / 256, 256, 0, stream>>>(Wq, Wk, Wv, compW, We, Bp);
    k_gemm<<<(N + 63) / 64, 256, 0, stream>>>(xb, Bp, compb, q, kb, vb, an, bn, Gb, N);
    k_tpn<<<(N + 3) / 4, 256, 0, stream>>>(tp, tpnb, N);
    k_logits<<<(E + 63) / 64, 256, 0, stream>>>(csrd, eattr, tpnb, q, kb, Gb,
                                                an, bn, alpha, E0, E);
    k_agg<<<(N + 3) / 4, 256, 0, stream>>>(csrd, rowp, alpha, vb, Wo, bo, out, N);
}

// Round 9
// 228.797 us; speedup vs baseline: 1.6577x; 1.1239x over previous
//
#include <hip/hip_runtime.h>
#include <math.h>

// N=50000 nodes, E0=800000 edges (+N self loops), IN=128, H=8, C=8 (HC=64), ED=16, T=96
// Node-side outputs are one MFMA GEMM: x[N][128] @ B[128][336] (q,k,v,an,bn,G).
// Edge phase: fused per-node kernel, chunked online softmax with LDS alpha staging.

struct __align__(8) US4 { unsigned short x, y, z, w; };

typedef __attribute__((ext_vector_type(8))) short bf16x8;
typedef __attribute__((ext_vector_type(4))) float f32x4;

#define CH 32

__device__ __forceinline__ unsigned short f2bf(float f) {
    unsigned u = __float_as_uint(f);
    unsigned r = (u + 0x7fffu + ((u >> 16) & 1u)) >> 16;
    return (unsigned short)r;
}
__device__ __forceinline__ float bf2f(unsigned short u) {
    return __uint_as_float(((unsigned)u) << 16);
}
__device__ __forceinline__ float blo(unsigned u) { return __uint_as_float(u << 16); }
__device__ __forceinline__ float bhi(unsigned u) { return __uint_as_float(u & 0xffff0000u); }

// ---------------- x -> bf16 ----------------
__global__ __launch_bounds__(256) void k_xcvt(const float* __restrict__ x,
                                              unsigned short* __restrict__ xb, int total4)
{
    int i = blockIdx.x * 256 + threadIdx.x;
    if (i >= total4) return;
    float4 v = ((const float4*)x)[i];
    US4 u = { f2bf(v.x), f2bf(v.y), f2bf(v.z), f2bf(v.w) };
    ((US4*)xb)[i] = u;
}

// ---------------- pack B fragments: Bp[((t*4+s)*64+lane)*8+i] ----------------
// col = t*16 + (lane&15); k = s*32 + (lane>>4)*8 + i
__global__ __launch_bounds__(256) void k_bpack(
    const float* __restrict__ Wq, const float* __restrict__ Wk, const float* __restrict__ Wv,
    const float* __restrict__ compW, const float* __restrict__ We,
    unsigned short* __restrict__ Bp)
{
    int gid = blockIdx.x * 256 + threadIdx.x;
    if (gid >= 21 * 2048) return;                 // 43008
    int i = gid & 7, lane = (gid >> 3) & 63, s = (gid >> 9) & 3, t = gid >> 11;
    int col = t * 16 + (lane & 15);
    int k = s * 32 + ((lane >> 4) << 3) + i;
    float v;
    if (col < 64)        v = Wq[col * 128 + k];
    else if (col < 128)  v = Wk[(col - 64) * 128 + k];
    else if (col < 192)  v = Wv[(col - 128) * 128 + k];
    else if (col < 200)  v = compW[(col - 192) * 256 + k];
    else if (col < 208)  v = compW[(col - 200) * 256 + 128 + k];
    else {
        int hd = col - 208, h = hd >> 4, d = hd & 15;
        v = 0.f;
        #pragma unroll
        for (int c = 0; c < 8; c++)
            v += Wk[(h * 8 + c) * 128 + k] * We[(h * 8 + c) * 16 + d];
    }
    Bp[gid] = f2bf(v);
}

// ---------------- MFMA projection GEMM: 64 rows/block, wave = 16-row subtile ----------------
__global__ __launch_bounds__(256) void k_gemm(
    const unsigned short* __restrict__ xb, const unsigned short* __restrict__ Bp,
    const float* __restrict__ compb,
    float* __restrict__ q, unsigned short* __restrict__ kb, unsigned short* __restrict__ vb,
    float* __restrict__ an, float* __restrict__ bn, unsigned short* __restrict__ Gb, int N)
{
    const int tid = threadIdx.x, w = tid >> 6, lane = tid & 63;
    const int half = lane >> 4;                   // 0..3
    const int c0 = lane & 15;
    int row_a = blockIdx.x * 64 + w * 16 + c0;
    int ra = min(row_a, N - 1);
    bf16x8 a0 = *(const bf16x8*)(xb + (size_t)ra * 128 +  0 + half * 8);
    bf16x8 a1 = *(const bf16x8*)(xb + (size_t)ra * 128 + 32 + half * 8);
    bf16x8 a2 = *(const bf16x8*)(xb + (size_t)ra * 128 + 64 + half * 8);
    bf16x8 a3 = *(const bf16x8*)(xb + (size_t)ra * 128 + 96 + half * 8);
    const int rbase = blockIdx.x * 64 + w * 16 + half * 4;
    const float cbv = compb[c0 & 7];

    for (int t = 0; t < 21; t++) {
        f32x4 acc = {0.f, 0.f, 0.f, 0.f};
        const bf16x8* bp = (const bf16x8*)(Bp + (size_t)((t * 4) * 64 + lane) * 8);
        acc = __builtin_amdgcn_mfma_f32_16x16x32_bf16(a0, bp[0],   acc, 0, 0, 0);
        acc = __builtin_amdgcn_mfma_f32_16x16x32_bf16(a1, bp[64],  acc, 0, 0, 0);
        acc = __builtin_amdgcn_mfma_f32_16x16x32_bf16(a2, bp[128], acc, 0, 0, 0);
        acc = __builtin_amdgcn_mfma_f32_16x16x32_bf16(a3, bp[192], acc, 0, 0, 0);
        #pragma unroll
        for (int r = 0; r < 4; r++) {
            int rr = rbase + r;
            if (rr >= N) continue;
            float vr = acc[r];
            if (t < 4)        q[(size_t)rr * 64 + t * 16 + c0] = vr * 0.35355339059327373f;
            else if (t < 8)   kb[(size_t)rr * 64 + (t - 4) * 16 + c0] = f2bf(vr);
            else if (t < 12)  vb[(size_t)rr * 64 + (t - 8) * 16 + c0] = f2bf(vr);
            else if (t == 12) {
                if (c0 < 8) an[(size_t)rr * 8 + c0] = vr;
                else        bn[(size_t)rr * 8 + (c0 - 8)] = vr + cbv;
            }
            else              Gb[(size_t)rr * 128 + (t - 13) * 16 + c0] = f2bf(vr);
        }
    }
}

// ---------------- temporal profile normalization (ddof=1) -> bf16, one wave per node ----------
__global__ __launch_bounds__(256) void k_tpn(const float* __restrict__ tp,
                                             unsigned short* __restrict__ tpnb, int N)
{
    int wave = threadIdx.x >> 6;
    int lane = threadIdx.x & 63;
    int n = blockIdx.x * 4 + wave;
    if (n >= N) return;
    const float* row = tp + (size_t)n * 96;
    float v0 = row[lane];
    float v1 = (lane < 32) ? row[64 + lane] : 0.f;
    float s = v0 + v1, ss = v0 * v0 + v1 * v1;
    #pragma unroll
    for (int m = 1; m < 64; m <<= 1) { s += __shfl_xor(s, m); ss += __shfl_xor(ss, m); }
    float mean = s * (1.f / 96.f);
    float var = (ss - 96.f * mean * mean) * (1.f / 95.f);
    var = fmaxf(var, 0.f);
    float inv = 1.f / (sqrtf(var) + 1e-8f);
    unsigned short* orow = tpnb + (size_t)n * 96;
    orow[lane] = f2bf((v0 - mean) * inv);
    if (lane < 32) orow[64 + lane] = f2bf((v1 - mean) * inv);
}

// ---------------- CSR build: histogram(+rank) / 3-stage scan / atomic-free scatter ----------
__global__ __launch_bounds__(256) void k_hist(const int* __restrict__ ei,
                                              int* __restrict__ deg,
                                              int* __restrict__ rnk, int E0, int N)
{
    int e = blockIdx.x * 256 + threadIdx.x;
    int E = E0 + N;
    if (e >= E) return;
    int dst = (e < E0) ? ei[E0 + e] : (e - E0);
    rnk[e] = atomicAdd(&deg[dst], 1);
}

__global__ __launch_bounds__(256) void k_scanA(const int* __restrict__ deg,
                                               int* __restrict__ bsum, int N)
{
    __shared__ int sm[256];
    int i = blockIdx.x * 256 + threadIdx.x;
    sm[threadIdx.x] = (i < N) ? deg[i] : 0;
    __syncthreads();
    for (int off = 128; off > 0; off >>= 1) {
        if (threadIdx.x < off) sm[threadIdx.x] += sm[threadIdx.x + off];
        __syncthreads();
    }
    if (threadIdx.x == 0) bsum[blockIdx.x] = sm[0];
}

__global__ __launch_bounds__(256) void k_scanB(int* __restrict__ bsum, int NB)
{
    __shared__ int sm[256];
    int t = threadIdx.x;
    sm[t] = (t < NB) ? bsum[t] : 0;
    __syncthreads();
    for (int off = 1; off < 256; off <<= 1) {
        int v = (t >= off) ? sm[t - off] : 0;
        __syncthreads();
        sm[t] += v;
        __syncthreads();
    }
    if (t < NB) bsum[t] = (t == 0) ? 0 : sm[t - 1];
}

__global__ __launch_bounds__(256) void k_scanC(const int* __restrict__ deg,
                                               const int* __restrict__ bsum,
                                               int* __restrict__ row, int N)
{
    __shared__ int sm[256];
    int b = blockIdx.x, t = threadIdx.x, i = b * 256 + t;
    int v = (i < N) ? deg[i] : 0;
    sm[t] = v;
    __syncthreads();
    for (int off = 1; off < 256; off <<= 1) {
        int u = (t >= off) ? sm[t - off] : 0;
        __syncthreads();
        sm[t] += u;
        __syncthreads();
    }
    int excl = bsum[b] + sm[t] - v;
    if (i < N) {
        row[i] = excl;
        if (i == N - 1) row[N] = excl + v;
    }
}

__global__ __launch_bounds__(256) void k_scatter(const int* __restrict__ ei,
                                                 const int* __restrict__ row,
                                                 const int* __restrict__ rnk,
                                                 int2* __restrict__ csrd, int E0, int N)
{
    int e = blockIdx.x * 256 + threadIdx.x;
    int E = E0 + N;
    if (e >= E) return;
    int src, dst;
    if (e < E0) { src = ei[e]; dst = ei[E0 + e]; }
    else        { src = e - E0; dst = src; }
    int pos = row[dst] + rnk[e];
    csrd[pos] = make_int2(e, src);
}

// ---------------- fused per-node attention: chunked online softmax, LDS alpha ----------------
// one wave per node (4/block). Phase L: 8 edges x 8 heads compute logits -> LDS.
// Accumulate: 8 edge-slots x 8 channel-blocks (lane&7 == head), uint4 vb gathers.
// Wave-synchronous: per-wave LDS regions, no __syncthreads.
__global__ __launch_bounds__(256) void k_nodeattn(
    const int2* __restrict__ csrd, const int* __restrict__ row,
    const float* __restrict__ eattr,
    const unsigned short* __restrict__ tpnb, const float* __restrict__ q,
    const unsigned short* __restrict__ kb, const unsigned short* __restrict__ Gb,
    const float* __restrict__ an, const float* __restrict__ bn,
    const unsigned short* __restrict__ vb,
    const float* __restrict__ Wo, const float* __restrict__ bo,
    float* __restrict__ out, int E0, int N)
{
    __shared__ float alsA[4][CH * 8];
    __shared__ int srcA[4][CH];
    const int tid = threadIdx.x;
    const int wave = tid >> 6, lane = tid & 63;
    const int n = blockIdx.x * 4 + wave;
    if (n >= N) return;
    float* als = alsA[wave];
    int* srcs = srcA[wave];

    const int beg = row[n], end = row[n + 1];
    const int h = lane & 7;           // head (both roles)
    const int g = lane >> 3;          // phase-L edge slot / accumulate edge slot

    // hoisted dst-side data (per head h)
    const float4* qp = (const float4*)(q + (size_t)n * 64 + h * 8);
    const float4 qd0 = qp[0], qd1 = qp[1];
    const uint2* tdp = (const uint2*)(tpnb + (size_t)n * 96 + h * 12);
    const uint2 td0 = tdp[0], td1 = tdp[1], td2 = tdp[2];
    const float bnh = bn[(size_t)n * 8 + h];

    float m_reg = -1e30f, dsum = 0.f;
    float acc[8];
    #pragma unroll
    for (int c = 0; c < 8; c++) acc[c] = 0.f;

    for (int cbeg = beg; cbeg < end; cbeg += CH) {
        const int cnt = min(CH, end - cbeg);

        // ---- phase L: logits for this chunk ----
        #pragma unroll
        for (int j = 0; j < 4; j++) {
            int eo = g + 8 * j;                       // uniform across the 8-lane group
            if (eo < cnt) {
                int2 es = csrd[cbeg + eo];
                const int e = es.x, s = es.y;

                const US4* kp = (const US4*)(kb + (size_t)s * 64 + h * 8);
                US4 k0 = kp[0], k1 = kp[1];
                float qk = qd0.x*bf2f(k0.x) + qd0.y*bf2f(k0.y) + qd0.z*bf2f(k0.z) + qd0.w*bf2f(k0.w)
                         + qd1.x*bf2f(k1.x) + qd1.y*bf2f(k1.y) + qd1.z*bf2f(k1.z) + qd1.w*bf2f(k1.w);

                const uint4* gp = (const uint4*)(Gb + (size_t)s * 128 + h * 16);
                uint4 g0 = gp[0], g1 = gp[1];
                int ec = (e < E0) ? e : 0;
                const float4* ep4 = (const float4*)(eattr + (size_t)ec * 16);
                float4 e0 = ep4[0], e1 = ep4[1], e2 = ep4[2], e3 = ep4[3];
                if (e >= E0) {
                    e0 = make_float4(1.f, 1.f, 1.f, 1.f); e1 = e0; e2 = e0; e3 = e0;
                }
                float efk = e0.x*blo(g0.x) + e0.y*bhi(g0.x) + e0.z*blo(g0.y) + e0.w*bhi(g0.y)
                          + e1.x*blo(g0.z) + e1.y*bhi(g0.z) + e1.z*blo(g0.w) + e1.w*bhi(g0.w)
                          + e2.x*blo(g1.x) + e2.y*bhi(g1.x) + e2.z*blo(g1.y) + e2.w*bhi(g1.y)
                          + e3.x*blo(g1.z) + e3.y*bhi(g1.z) + e3.z*blo(g1.w) + e3.w*bhi(g1.w);

                float tv = an[(size_t)s * 8 + h] + bnh;
                float ex = __expf(2.f * tv);
                float tn = 1.f - 2.f / (ex + 1.f);

                const uint2* tsp = (const uint2*)(tpnb + (size_t)s * 96 + h * 12);
                uint2 s0 = tsp[0], s1 = tsp[1], s2 = tsp[2];
                float pc = blo(s0.x)*blo(td0.x) + bhi(s0.x)*bhi(td0.x)
                         + blo(s0.y)*blo(td0.y) + bhi(s0.y)*bhi(td0.y)
                         + blo(s1.x)*blo(td1.x) + bhi(s1.x)*bhi(td1.x)
                         + blo(s1.y)*blo(td1.y) + bhi(s1.y)*bhi(td1.y)
                         + blo(s2.x)*blo(td2.x) + bhi(s2.x)*bhi(td2.x)
                         + blo(s2.y)*blo(td2.y) + bhi(s2.y)*bhi(td2.y);
                float cv = pc * (-0.25f / 96.f) + tn * (-0.25f / 8.f);
                cv += __shfl_xor(cv, 1); cv += __shfl_xor(cv, 2); cv += __shfl_xor(cv, 4);

                float a = qk + efk + cv;
                a = fmaxf(a, 0.2f * a);                // leaky relu
                als[eo * 8 + h] = a;                   // addr = lane + 64j (conflict-free)
                if (h == 0) srcs[eo] = s;
            }
        }

        // ---- chunk max per head (every lane ends with max for its h) ----
        float mloc = -1e30f;
        #pragma unroll
        for (int r = 0; r < 4; r++) {
            int eo = g + 8 * r;
            if (eo < cnt) mloc = fmaxf(mloc, als[eo * 8 + h]);
        }
        mloc = fmaxf(mloc, __shfl_xor(mloc, 8));
        mloc = fmaxf(mloc, __shfl_xor(mloc, 16));
        mloc = fmaxf(mloc, __shfl_xor(mloc, 32));

        // ---- online merge + accumulate (slot = g, channel block = h) ----
        float mn = fmaxf(m_reg, mloc);
        float sc = __expf(m_reg - mn);
        m_reg = mn;
        dsum *= sc;
        #pragma unroll
        for (int c = 0; c < 8; c++) acc[c] *= sc;

        for (int i = g; i < cnt; i += 8) {
            float av = als[i * 8 + h];                 // addr = lane + 64*it (conflict-free)
            int s = srcs[i];
            uint4 vu = *(const uint4*)(vb + (size_t)s * 64 + h * 8);
            float p = __expf(av - mn);
            dsum += p;
            acc[0] += p * blo(vu.x); acc[1] += p * bhi(vu.x);
            acc[2] += p * blo(vu.y); acc[3] += p * bhi(vu.y);
            acc[4] += p * blo(vu.z); acc[5] += p * bhi(vu.z);
            acc[6] += p * blo(vu.w); acc[7] += p * bhi(vu.w);
        }
    }

    // ---- merge slots (bits 3-5): per-head denom + channel sums ----
    dsum += __shfl_xor(dsum, 8); dsum += __shfl_xor(dsum, 16); dsum += __shfl_xor(dsum, 32);
    #pragma unroll
    for (int c = 0; c < 8; c++) {
        acc[c] += __shfl_xor(acc[c], 8);
        acc[c] += __shfl_xor(acc[c], 16);
        acc[c] += __shfl_xor(acc[c], 32);
    }
    float inv = 1.f / (dsum + 1e-16f);

    // ---- fused Wo projection: lane holds channels h*8..h*8+7 ----
    float po[8];
    #pragma unroll
    for (int cp8 = 0; cp8 < 8; cp8++) {
        const float4* wr = (const float4*)(Wo + cp8 * 64 + h * 8);
        float4 w0 = wr[0], w1 = wr[1];
        po[cp8] = inv * (acc[0]*w0.x + acc[1]*w0.y + acc[2]*w0.z + acc[3]*w0.w
                       + acc[4]*w1.x + acc[5]*w1.y + acc[6]*w1.z + acc[7]*w1.w);
    }
    #pragma unroll
    for (int cp8 = 0; cp8 < 8; cp8++) {
        po[cp8] += __shfl_xor(po[cp8], 1);
        po[cp8] += __shfl_xor(po[cp8], 2);
        po[cp8] += __shfl_xor(po[cp8], 4);
    }
    if (lane < 8) out[(size_t)n * 8 + lane] = po[lane] + bo[lane];
}

extern "C" void kernel_launch(void* const* d_in, const int* in_sizes, int n_in,
                              void* d_out, int out_size, void* d_ws, size_t ws_size,
                              hipStream_t stream)
{
    const float* x     = (const float*)d_in[0];
    const int*   ei    = (const int*)d_in[1];
    const float* eattr = (const float*)d_in[2];
    const float* tp    = (const float*)d_in[3];
    const float* Wq    = (const float*)d_in[4];
    const float* Wk    = (const float*)d_in[5];
    const float* Wv    = (const float*)d_in[6];
    const float* We    = (const float*)d_in[7];
    const float* compW = (const float*)d_in[8];
    const float* compb = (const float*)d_in[9];
    const float* Wo    = (const float*)d_in[10];
    const float* bo    = (const float*)d_in[11];
    float* out = (float*)d_out;

    const int N  = in_sizes[0] / 128;
    const int E0 = in_sizes[1] / 2;
    const int E  = E0 + N;
    const int NB = (N + 255) / 256;

    float* ws = (float*)d_ws;
    size_t off = 0;
    unsigned short* tpnb = (unsigned short*)(ws + off); off += (size_t)N * 48;   // N*96 ushort
    float* q  = ws + off; off += (size_t)N * 64;
    unsigned short* kb = (unsigned short*)(ws + off); off += (size_t)N * 32;     // N*64 ushort
    unsigned short* vb = (unsigned short*)(ws + off); off += (size_t)N * 32;
    unsigned short* Gb = (unsigned short*)(ws + off); off += (size_t)N * 64;     // N*128 ushort
    float* an = ws + off; off += (size_t)N * 8;
    float* bn = ws + off; off += (size_t)N * 8;
    int* deg    = (int*)(ws + off); off += N;
    int* bsum   = (int*)(ws + off); off += 256;
    int* rowp   = (int*)(ws + off); off += N + 4;
    unsigned short* Bp = (unsigned short*)(ws + off); off += 21504;              // 43008 ushort
    int2* csrd  = (int2*)(ws + off); off += (size_t)E * 2;
    int* rnk    = (int*)(ws + off); off += E;
    unsigned short* xb = (unsigned short*)(ws + off); off += (size_t)N * 64;     // N*128 ushort

    hipMemsetAsync(deg, 0, (size_t)N * sizeof(int), stream);

    k_hist<<<(E + 255) / 256, 256, 0, stream>>>(ei, deg, rnk, E0, N);
    k_scanA<<<NB, 256, 0, stream>>>(deg, bsum, N);
    k_scanB<<<1, 256, 0, stream>>>(bsum, NB);
    k_scanC<<<NB, 256, 0, stream>>>(deg, bsum, rowp, N);
    k_scatter<<<(E + 255) / 256, 256, 0, stream>>>(ei, rowp, rnk, csrd, E0, N);

    k_xcvt<<<((size_t)N * 32 + 255) / 256, 256, 0, stream>>>(x, xb, N * 32);
    k_bpack<<<(21 * 2048 + 255) / 256, 256, 0, stream>>>(Wq, Wk, Wv, compW, We, Bp);
    k_gemm<<<(N + 63) / 64, 256, 0, stream>>>(xb, Bp, compb, q, kb, vb, an, bn, Gb, N);
    k_tpn<<<(N + 3) / 4, 256, 0, stream>>>(tp, tpnb, N);

    k_nodeattn<<<(N + 3) / 4, 256, 0, stream>>>(csrd, rowp, eattr, tpnb, q, kb, Gb,
                                                an, bn, vb, Wo, bo, out, E0, N);
}

// Round 10
// 221.851 us; speedup vs baseline: 1.7096x; 1.0313x over previous
//
#include <hip/hip_runtime.h>
#include <math.h>

// N=50000 nodes, E0=800000 edges (+N self loops), IN=128, H=8, C=8 (HC=64), ED=16, T=96
// Node-side outputs are one MFMA GEMM: x[N][128] @ B[128][336] (q,k,v,an,bn,G).
// Edge phase: fused per-node kernel, chunked online softmax, all-register (no LDS).

struct __align__(8) US4 { unsigned short x, y, z, w; };

typedef __attribute__((ext_vector_type(8))) short bf16x8;
typedef __attribute__((ext_vector_type(4))) float f32x4;

#define CH 32

__device__ __forceinline__ unsigned short f2bf(float f) {
    unsigned u = __float_as_uint(f);
    unsigned r = (u + 0x7fffu + ((u >> 16) & 1u)) >> 16;
    return (unsigned short)r;
}
__device__ __forceinline__ float bf2f(unsigned short u) {
    return __uint_as_float(((unsigned)u) << 16);
}
__device__ __forceinline__ float blo(unsigned u) { return __uint_as_float(u << 16); }
__device__ __forceinline__ float bhi(unsigned u) { return __uint_as_float(u & 0xffff0000u); }

// ---------------- pack B fragments: Bp[((t*4+s)*64+lane)*8+i] ----------------
// col = t*16 + (lane&15); k = s*32 + (lane>>4)*8 + i
__global__ __launch_bounds__(256) void k_bpack(
    const float* __restrict__ Wq, const float* __restrict__ Wk, const float* __restrict__ Wv,
    const float* __restrict__ compW, const float* __restrict__ We,
    unsigned short* __restrict__ Bp)
{
    int gid = blockIdx.x * 256 + threadIdx.x;
    if (gid >= 21 * 2048) return;                 // 43008
    int i = gid & 7, lane = (gid >> 3) & 63, s = (gid >> 9) & 3, t = gid >> 11;
    int col = t * 16 + (lane & 15);
    int k = s * 32 + ((lane >> 4) << 3) + i;
    float v;
    if (col < 64)        v = Wq[col * 128 + k];
    else if (col < 128)  v = Wk[(col - 64) * 128 + k];
    else if (col < 192)  v = Wv[(col - 128) * 128 + k];
    else if (col < 200)  v = compW[(col - 192) * 256 + k];
    else if (col < 208)  v = compW[(col - 200) * 256 + 128 + k];
    else {
        int hd = col - 208, h = hd >> 4, d = hd & 15;
        v = 0.f;
        #pragma unroll
        for (int c = 0; c < 8; c++)
            v += Wk[(h * 8 + c) * 128 + k] * We[(h * 8 + c) * 16 + d];
    }
    Bp[gid] = f2bf(v);
}

__device__ __forceinline__ bf16x8 ld_bf8(const float* p) {
    float4 a = ((const float4*)p)[0], b = ((const float4*)p)[1];
    bf16x8 r;
    r[0] = (short)f2bf(a.x); r[1] = (short)f2bf(a.y);
    r[2] = (short)f2bf(a.z); r[3] = (short)f2bf(a.w);
    r[4] = (short)f2bf(b.x); r[5] = (short)f2bf(b.y);
    r[6] = (short)f2bf(b.z); r[7] = (short)f2bf(b.w);
    return r;
}

// ---------------- MFMA projection GEMM (x f32 read + in-reg bf16 cvt) ----------------
__global__ __launch_bounds__(256) void k_gemm(
    const float* __restrict__ x, const unsigned short* __restrict__ Bp,
    const float* __restrict__ compb,
    float* __restrict__ q, unsigned short* __restrict__ kb, unsigned short* __restrict__ vb,
    float* __restrict__ an, float* __restrict__ bn, unsigned short* __restrict__ Gb, int N)
{
    const int tid = threadIdx.x, w = tid >> 6, lane = tid & 63;
    const int half = lane >> 4;                   // 0..3
    const int c0 = lane & 15;
    int row_a = blockIdx.x * 64 + w * 16 + c0;
    int ra = min(row_a, N - 1);
    const float* xr = x + (size_t)ra * 128 + half * 8;
    bf16x8 a0 = ld_bf8(xr +  0);
    bf16x8 a1 = ld_bf8(xr + 32);
    bf16x8 a2 = ld_bf8(xr + 64);
    bf16x8 a3 = ld_bf8(xr + 96);
    const int rbase = blockIdx.x * 64 + w * 16 + half * 4;
    const float cbv = compb[c0 & 7];

    for (int t = 0; t < 21; t++) {
        f32x4 acc = {0.f, 0.f, 0.f, 0.f};
        const bf16x8* bp = (const bf16x8*)(Bp + (size_t)((t * 4) * 64 + lane) * 8);
        acc = __builtin_amdgcn_mfma_f32_16x16x32_bf16(a0, bp[0],   acc, 0, 0, 0);
        acc = __builtin_amdgcn_mfma_f32_16x16x32_bf16(a1, bp[64],  acc, 0, 0, 0);
        acc = __builtin_amdgcn_mfma_f32_16x16x32_bf16(a2, bp[128], acc, 0, 0, 0);
        acc = __builtin_amdgcn_mfma_f32_16x16x32_bf16(a3, bp[192], acc, 0, 0, 0);
        #pragma unroll
        for (int r = 0; r < 4; r++) {
            int rr = rbase + r;
            if (rr >= N) continue;
            float vr = acc[r];
            if (t < 4)        q[(size_t)rr * 64 + t * 16 + c0] = vr * 0.35355339059327373f;
            else if (t < 8)   kb[(size_t)rr * 64 + (t - 4) * 16 + c0] = f2bf(vr);
            else if (t < 12)  vb[(size_t)rr * 64 + (t - 8) * 16 + c0] = f2bf(vr);
            else if (t == 12) {
                if (c0 < 8) an[(size_t)rr * 8 + c0] = vr;
                else        bn[(size_t)rr * 8 + (c0 - 8)] = vr + cbv;
            }
            else              Gb[(size_t)rr * 128 + (t - 13) * 16 + c0] = f2bf(vr);
        }
    }
}

// ---------------- temporal profile normalization (ddof=1) -> bf16, one wave per node ----------
__global__ __launch_bounds__(256) void k_tpn(const float* __restrict__ tp,
                                             unsigned short* __restrict__ tpnb, int N)
{
    int wave = threadIdx.x >> 6;
    int lane = threadIdx.x & 63;
    int n = blockIdx.x * 4 + wave;
    if (n >= N) return;
    const float* row = tp + (size_t)n * 96;
    float v0 = row[lane];
    float v1 = (lane < 32) ? row[64 + lane] : 0.f;
    float s = v0 + v1, ss = v0 * v0 + v1 * v1;
    #pragma unroll
    for (int m = 1; m < 64; m <<= 1) { s += __shfl_xor(s, m); ss += __shfl_xor(ss, m); }
    float mean = s * (1.f / 96.f);
    float var = (ss - 96.f * mean * mean) * (1.f / 95.f);
    var = fmaxf(var, 0.f);
    float inv = 1.f / (sqrtf(var) + 1e-8f);
    unsigned short* orow = tpnb + (size_t)n * 96;
    orow[lane] = f2bf((v0 - mean) * inv);
    if (lane < 32) orow[64 + lane] = f2bf((v1 - mean) * inv);
}

// ---------------- CSR build: histogram(+rank) / 3-stage scan / atomic-free scatter ----------
__global__ __launch_bounds__(256) void k_hist(const int* __restrict__ ei,
                                              int* __restrict__ deg,
                                              int* __restrict__ rnk, int E0, int N)
{
    int e = blockIdx.x * 256 + threadIdx.x;
    int E = E0 + N;
    if (e >= E) return;
    int dst = (e < E0) ? ei[E0 + e] : (e - E0);
    rnk[e] = atomicAdd(&deg[dst], 1);
}

__global__ __launch_bounds__(256) void k_scanA(const int* __restrict__ deg,
                                               int* __restrict__ bsum, int N)
{
    __shared__ int sm[256];
    int i = blockIdx.x * 256 + threadIdx.x;
    sm[threadIdx.x] = (i < N) ? deg[i] : 0;
    __syncthreads();
    for (int off = 128; off > 0; off >>= 1) {
        if (threadIdx.x < off) sm[threadIdx.x] += sm[threadIdx.x + off];
        __syncthreads();
    }
    if (threadIdx.x == 0) bsum[blockIdx.x] = sm[0];
}

__global__ __launch_bounds__(256) void k_scanB(int* __restrict__ bsum, int NB)
{
    __shared__ int sm[256];
    int t = threadIdx.x;
    sm[t] = (t < NB) ? bsum[t] : 0;
    __syncthreads();
    for (int off = 1; off < 256; off <<= 1) {
        int v = (t >= off) ? sm[t - off] : 0;
        __syncthreads();
        sm[t] += v;
        __syncthreads();
    }
    if (t < NB) bsum[t] = (t == 0) ? 0 : sm[t - 1];
}

__global__ __launch_bounds__(256) void k_scanC(const int* __restrict__ deg,
                                               const int* __restrict__ bsum,
                                               int* __restrict__ row, int N)
{
    __shared__ int sm[256];
    int b = blockIdx.x, t = threadIdx.x, i = b * 256 + t;
    int v = (i < N) ? deg[i] : 0;
    sm[t] = v;
    __syncthreads();
    for (int off = 1; off < 256; off <<= 1) {
        int u = (t >= off) ? sm[t - off] : 0;
        __syncthreads();
        sm[t] += u;
        __syncthreads();
    }
    int excl = bsum[b] + sm[t] - v;
    if (i < N) {
        row[i] = excl;
        if (i == N - 1) row[N] = excl + v;
    }
}

__global__ __launch_bounds__(256) void k_scatter(const int* __restrict__ ei,
                                                 const int* __restrict__ row,
                                                 const int* __restrict__ rnk,
                                                 int2* __restrict__ csrd, int E0, int N)
{
    int e = blockIdx.x * 256 + threadIdx.x;
    int E = E0 + N;
    if (e >= E) return;
    int src, dst;
    if (e < E0) { src = ei[e]; dst = ei[E0 + e]; }
    else        { src = e - E0; dst = src; }
    int pos = row[dst] + rnk[e];
    csrd[pos] = make_int2(e, src);
}

// ---------------- fused per-node attention: chunked online softmax, all-register ----------
// one wave per node (4/block). lane = g*8+h: group g = edge slot, h = head (phase L)
// and h = channel block (accumulate). Same lane computes and consumes alpha/vb -> registers.
__global__ __launch_bounds__(256) void k_nodeattn(
    const int2* __restrict__ csrd, const int* __restrict__ row,
    const float* __restrict__ eattr,
    const unsigned short* __restrict__ tpnb, const float* __restrict__ q,
    const unsigned short* __restrict__ kb, const unsigned short* __restrict__ Gb,
    const float* __restrict__ an, const float* __restrict__ bn,
    const unsigned short* __restrict__ vb,
    const float* __restrict__ Wo, const float* __restrict__ bo,
    float* __restrict__ out, int E0, int N)
{
    const int tid = threadIdx.x;
    const int wave = tid >> 6, lane = tid & 63;
    const int n = blockIdx.x * 4 + wave;
    if (n >= N) return;

    const int beg = row[n], end = row[n + 1];
    const int h = lane & 7;           // head / channel block
    const int g = lane >> 3;          // edge slot

    // hoisted dst-side data (per head h)
    const float4* qp = (const float4*)(q + (size_t)n * 64 + h * 8);
    const float4 qd0 = qp[0], qd1 = qp[1];
    const uint2* tdp = (const uint2*)(tpnb + (size_t)n * 96 + h * 12);
    const uint2 td0 = tdp[0], td1 = tdp[1], td2 = tdp[2];
    const float bnh = bn[(size_t)n * 8 + h];

    float m_reg = -1e30f, dsum = 0.f;
    float acc[8];
    #pragma unroll
    for (int c = 0; c < 8; c++) acc[c] = 0.f;

    for (int cbeg = beg; cbeg < end; cbeg += CH) {
        const int cnt = min(CH, end - cbeg);

        float av[4];
        uint4 vu[4];
        // ---- phase L: logits + vb prefetch for this chunk (registers only) ----
        #pragma unroll
        for (int j = 0; j < 4; j++) {
            av[j] = -1e30f;
            vu[j] = make_uint4(0u, 0u, 0u, 0u);
            int eo = g + 8 * j;
            if (eo < cnt) {
                int2 es = csrd[cbeg + eo];
                const int e = es.x, s = es.y;

                vu[j] = *(const uint4*)(vb + (size_t)s * 64 + h * 8);   // prefetch V

                const US4* kp = (const US4*)(kb + (size_t)s * 64 + h * 8);
                US4 k0 = kp[0], k1 = kp[1];
                float qk = qd0.x*bf2f(k0.x) + qd0.y*bf2f(k0.y) + qd0.z*bf2f(k0.z) + qd0.w*bf2f(k0.w)
                         + qd1.x*bf2f(k1.x) + qd1.y*bf2f(k1.y) + qd1.z*bf2f(k1.z) + qd1.w*bf2f(k1.w);

                const uint4* gp = (const uint4*)(Gb + (size_t)s * 128 + h * 16);
                uint4 g0 = gp[0], g1 = gp[1];
                int ec = (e < E0) ? e : 0;
                const float4* ep4 = (const float4*)(eattr + (size_t)ec * 16);
                float4 e0 = ep4[0], e1 = ep4[1], e2 = ep4[2], e3 = ep4[3];
                if (e >= E0) {
                    e0 = make_float4(1.f, 1.f, 1.f, 1.f); e1 = e0; e2 = e0; e3 = e0;
                }
                float efk = e0.x*blo(g0.x) + e0.y*bhi(g0.x) + e0.z*blo(g0.y) + e0.w*bhi(g0.y)
                          + e1.x*blo(g0.z) + e1.y*bhi(g0.z) + e1.z*blo(g0.w) + e1.w*bhi(g0.w)
                          + e2.x*blo(g1.x) + e2.y*bhi(g1.x) + e2.z*blo(g1.y) + e2.w*bhi(g1.y)
                          + e3.x*blo(g1.z) + e3.y*bhi(g1.z) + e3.z*blo(g1.w) + e3.w*bhi(g1.w);

                float tv = an[(size_t)s * 8 + h] + bnh;
                float ex = __expf(2.f * tv);
                float tn = 1.f - 2.f / (ex + 1.f);

                const uint2* tsp = (const uint2*)(tpnb + (size_t)s * 96 + h * 12);
                uint2 s0 = tsp[0], s1 = tsp[1], s2 = tsp[2];
                float pc = blo(s0.x)*blo(td0.x) + bhi(s0.x)*bhi(td0.x)
                         + blo(s0.y)*blo(td0.y) + bhi(s0.y)*bhi(td0.y)
                         + blo(s1.x)*blo(td1.x) + bhi(s1.x)*bhi(td1.x)
                         + blo(s1.y)*blo(td1.y) + bhi(s1.y)*bhi(td1.y)
                         + blo(s2.x)*blo(td2.x) + bhi(s2.x)*bhi(td2.x)
                         + blo(s2.y)*blo(td2.y) + bhi(s2.y)*bhi(td2.y);
                float cv = pc * (-0.25f / 96.f) + tn * (-0.25f / 8.f);
                cv += __shfl_xor(cv, 1); cv += __shfl_xor(cv, 2); cv += __shfl_xor(cv, 4);

                float a = qk + efk + cv;
                av[j] = fmaxf(a, 0.2f * a);            // leaky relu
            }
        }

        // ---- chunk max per head (across groups: lane bits 3-5) ----
        float mloc = fmaxf(fmaxf(av[0], av[1]), fmaxf(av[2], av[3]));
        mloc = fmaxf(mloc, __shfl_xor(mloc, 8));
        mloc = fmaxf(mloc, __shfl_xor(mloc, 16));
        mloc = fmaxf(mloc, __shfl_xor(mloc, 32));

        // ---- online merge + accumulate (all register) ----
        float mn = fmaxf(m_reg, mloc);
        float sc = __expf(m_reg - mn);
        m_reg = mn;
        dsum *= sc;
        #pragma unroll
        for (int c = 0; c < 8; c++) acc[c] *= sc;

        #pragma unroll
        for (int j = 0; j < 4; j++) {
            float p = __expf(av[j] - mn);              // 0 for inactive slots
            dsum += p;
            acc[0] += p * blo(vu[j].x); acc[1] += p * bhi(vu[j].x);
            acc[2] += p * blo(vu[j].y); acc[3] += p * bhi(vu[j].y);
            acc[4] += p * blo(vu[j].z); acc[5] += p * bhi(vu[j].z);
            acc[6] += p * blo(vu[j].w); acc[7] += p * bhi(vu[j].w);
        }
    }

    // ---- merge slots (bits 3-5): per-head denom + channel sums ----
    dsum += __shfl_xor(dsum, 8); dsum += __shfl_xor(dsum, 16); dsum += __shfl_xor(dsum, 32);
    #pragma unroll
    for (int c = 0; c < 8; c++) {
        acc[c] += __shfl_xor(acc[c], 8);
        acc[c] += __shfl_xor(acc[c], 16);
        acc[c] += __shfl_xor(acc[c], 32);
    }
    float inv = 1.f / (dsum + 1e-16f);

    // ---- fused Wo projection: lane holds channels h*8..h*8+7 ----
    float po[8];
    #pragma unroll
    for (int cp8 = 0; cp8 < 8; cp8++) {
        const float4* wr = (const float4*)(Wo + cp8 * 64 + h * 8);
        float4 w0 = wr[0], w1 = wr[1];
        po[cp8] = inv * (acc[0]*w0.x + acc[1]*w0.y + acc[2]*w0.z + acc[3]*w0.w
                       + acc[4]*w1.x + acc[5]*w1.y + acc[6]*w1.z + acc[7]*w1.w);
    }
    #pragma unroll
    for (int cp8 = 0; cp8 < 8; cp8++) {
        po[cp8] += __shfl_xor(po[cp8], 1);
        po[cp8] += __shfl_xor(po[cp8], 2);
        po[cp8] += __shfl_xor(po[cp8], 4);
    }
    if (lane < 8) out[(size_t)n * 8 + lane] = po[lane] + bo[lane];
}

extern "C" void kernel_launch(void* const* d_in, const int* in_sizes, int n_in,
                              void* d_out, int out_size, void* d_ws, size_t ws_size,
                              hipStream_t stream)
{
    const float* x     = (const float*)d_in[0];
    const int*   ei    = (const int*)d_in[1];
    const float* eattr = (const float*)d_in[2];
    const float* tp    = (const float*)d_in[3];
    const float* Wq    = (const float*)d_in[4];
    const float* Wk    = (const float*)d_in[5];
    const float* Wv    = (const float*)d_in[6];
    const float* We    = (const float*)d_in[7];
    const float* compW = (const float*)d_in[8];
    const float* compb = (const float*)d_in[9];
    const float* Wo    = (const float*)d_in[10];
    const float* bo    = (const float*)d_in[11];
    float* out = (float*)d_out;

    const int N  = in_sizes[0] / 128;
    const int E0 = in_sizes[1] / 2;
    const int E  = E0 + N;
    const int NB = (N + 255) / 256;

    float* ws = (float*)d_ws;
    size_t off = 0;
    unsigned short* tpnb = (unsigned short*)(ws + off); off += (size_t)N * 48;   // N*96 ushort
    float* q  = ws + off; off += (size_t)N * 64;
    unsigned short* kb = (unsigned short*)(ws + off); off += (size_t)N * 32;     // N*64 ushort
    unsigned short* vb = (unsigned short*)(ws + off); off += (size_t)N * 32;
    unsigned short* Gb = (unsigned short*)(ws + off); off += (size_t)N * 64;     // N*128 ushort
    float* an = ws + off; off += (size_t)N * 8;
    float* bn = ws + off; off += (size_t)N * 8;
    int* deg    = (int*)(ws + off); off += N;
    int* bsum   = (int*)(ws + off); off += 256;
    int* rowp   = (int*)(ws + off); off += N + 4;
    unsigned short* Bp = (unsigned short*)(ws + off); off += 21504;              // 43008 ushort
    int2* csrd  = (int2*)(ws + off); off += (size_t)E * 2;
    int* rnk    = (int*)(ws + off); off += E;

    hipMemsetAsync(deg, 0, (size_t)N * sizeof(int), stream);

    k_hist<<<(E + 255) / 256, 256, 0, stream>>>(ei, deg, rnk, E0, N);
    k_scanA<<<NB, 256, 0, stream>>>(deg, bsum, N);
    k_scanB<<<1, 256, 0, stream>>>(bsum, NB);
    k_scanC<<<NB, 256, 0, stream>>>(deg, bsum, rowp, N);
    k_scatter<<<(E + 255) / 256, 256, 0, stream>>>(ei, rowp, rnk, csrd, E0, N);

    k_bpack<<<(21 * 2048 + 255) / 256, 256, 0, stream>>>(Wq, Wk, Wv, compW, We, Bp);
    k_gemm<<<(N + 63) / 64, 256, 0, stream>>>(x, Bp, compb, q, kb, vb, an, bn, Gb, N);
    k_tpn<<<(N + 3) / 4, 256, 0, stream>>>(tp, tpnb, N);

    k_nodeattn<<<(N + 3) / 4, 256, 0, stream>>>(csrd, rowp, eattr, tpnb, q, kb, Gb,
                                                an, bn, vb, Wo, bo, out, E0, N);
}

// Round 11
// 219.702 us; speedup vs baseline: 1.7264x; 1.0098x over previous
//
#include <hip/hip_runtime.h>
#include <math.h>

// N=50000 nodes, E0=800000 edges (+N self loops), IN=128, H=8, C=8 (HC=64), ED=16, T=96
// Node data lives in ONE interleaved 768B record per node (6 cache lines):
//   ushort offsets: kb 0-63 | Gb 64-191 | vb 192-255 | tpn 256-351 | an(f32) 352-367 | bn(f32) 368-383
// Projections via one MFMA GEMM x[N][128] @ B[128][336]; edge phase fused per-node
// (chunked online softmax, all-register).

struct __align__(8) US4 { unsigned short x, y, z, w; };

typedef __attribute__((ext_vector_type(8))) short bf16x8;
typedef __attribute__((ext_vector_type(4))) float f32x4;

#define CH 32

__device__ __forceinline__ unsigned short f2bf(float f) {
    unsigned u = __float_as_uint(f);
    unsigned r = (u + 0x7fffu + ((u >> 16) & 1u)) >> 16;
    return (unsigned short)r;
}
__device__ __forceinline__ float bf2f(unsigned short u) {
    return __uint_as_float(((unsigned)u) << 16);
}
__device__ __forceinline__ float blo(unsigned u) { return __uint_as_float(u << 16); }
__device__ __forceinline__ float bhi(unsigned u) { return __uint_as_float(u & 0xffff0000u); }

// ---------------- pack B fragments: Bp[((t*4+s)*64+lane)*8+i] ----------------
__global__ __launch_bounds__(256) void k_bpack(
    const float* __restrict__ Wq, const float* __restrict__ Wk, const float* __restrict__ Wv,
    const float* __restrict__ compW, const float* __restrict__ We,
    unsigned short* __restrict__ Bp)
{
    int gid = blockIdx.x * 256 + threadIdx.x;
    if (gid >= 21 * 2048) return;                 // 43008
    int i = gid & 7, lane = (gid >> 3) & 63, s = (gid >> 9) & 3, t = gid >> 11;
    int col = t * 16 + (lane & 15);
    int k = s * 32 + ((lane >> 4) << 3) + i;
    float v;
    if (col < 64)        v = Wq[col * 128 + k];
    else if (col < 128)  v = Wk[(col - 64) * 128 + k];
    else if (col < 192)  v = Wv[(col - 128) * 128 + k];
    else if (col < 200)  v = compW[(col - 192) * 256 + k];
    else if (col < 208)  v = compW[(col - 200) * 256 + 128 + k];
    else {
        int hd = col - 208, h = hd >> 4, d = hd & 15;
        v = 0.f;
        #pragma unroll
        for (int c = 0; c < 8; c++)
            v += Wk[(h * 8 + c) * 128 + k] * We[(h * 8 + c) * 16 + d];
    }
    Bp[gid] = f2bf(v);
}

__device__ __forceinline__ bf16x8 ld_bf8(const float* p) {
    float4 a = ((const float4*)p)[0], b = ((const float4*)p)[1];
    bf16x8 r;
    r[0] = (short)f2bf(a.x); r[1] = (short)f2bf(a.y);
    r[2] = (short)f2bf(a.z); r[3] = (short)f2bf(a.w);
    r[4] = (short)f2bf(b.x); r[5] = (short)f2bf(b.y);
    r[6] = (short)f2bf(b.z); r[7] = (short)f2bf(b.w);
    return r;
}

// ---------------- MFMA projection GEMM -> q (separate) + interleaved record ----------------
__global__ __launch_bounds__(256) void k_gemm(
    const float* __restrict__ x, const unsigned short* __restrict__ Bp,
    const float* __restrict__ compb,
    float* __restrict__ q, unsigned short* __restrict__ rec, int N)
{
    const int tid = threadIdx.x, w = tid >> 6, lane = tid & 63;
    const int half = lane >> 4;                   // 0..3
    const int c0 = lane & 15;
    int row_a = blockIdx.x * 64 + w * 16 + c0;
    int ra = min(row_a, N - 1);
    const float* xr = x + (size_t)ra * 128 + half * 8;
    bf16x8 a0 = ld_bf8(xr +  0);
    bf16x8 a1 = ld_bf8(xr + 32);
    bf16x8 a2 = ld_bf8(xr + 64);
    bf16x8 a3 = ld_bf8(xr + 96);
    const int rbase = blockIdx.x * 64 + w * 16 + half * 4;
    const float cbv = compb[c0 & 7];

    for (int t = 0; t < 21; t++) {
        f32x4 acc = {0.f, 0.f, 0.f, 0.f};
        const bf16x8* bp = (const bf16x8*)(Bp + (size_t)((t * 4) * 64 + lane) * 8);
        acc = __builtin_amdgcn_mfma_f32_16x16x32_bf16(a0, bp[0],   acc, 0, 0, 0);
        acc = __builtin_amdgcn_mfma_f32_16x16x32_bf16(a1, bp[64],  acc, 0, 0, 0);
        acc = __builtin_amdgcn_mfma_f32_16x16x32_bf16(a2, bp[128], acc, 0, 0, 0);
        acc = __builtin_amdgcn_mfma_f32_16x16x32_bf16(a3, bp[192], acc, 0, 0, 0);
        #pragma unroll
        for (int r = 0; r < 4; r++) {
            int rr = rbase + r;
            if (rr >= N) continue;
            float vr = acc[r];
            unsigned short* recR = rec + (size_t)rr * 384;
            if (t < 4)        q[(size_t)rr * 64 + t * 16 + c0] = vr * 0.35355339059327373f;
            else if (t < 8)   recR[(t - 4) * 16 + c0] = f2bf(vr);            // kb
            else if (t < 12)  recR[192 + (t - 8) * 16 + c0] = f2bf(vr);      // vb
            else if (t == 12) {
                if (c0 < 8) ((float*)(recR + 352))[c0] = vr;                 // an
                else        ((float*)(recR + 368))[c0 - 8] = vr + cbv;       // bn (+comp_b)
            }
            else              recR[64 + (t - 13) * 16 + c0] = f2bf(vr);      // Gb
        }
    }
}

// ---------------- tpn (ddof=1) -> bf16 into record, one wave per node ----------
__global__ __launch_bounds__(256) void k_tpn(const float* __restrict__ tp,
                                             unsigned short* __restrict__ rec, int N)
{
    int wave = threadIdx.x >> 6;
    int lane = threadIdx.x & 63;
    int n = blockIdx.x * 4 + wave;
    if (n >= N) return;
    const float* row = tp + (size_t)n * 96;
    float v0 = row[lane];
    float v1 = (lane < 32) ? row[64 + lane] : 0.f;
    float s = v0 + v1, ss = v0 * v0 + v1 * v1;
    #pragma unroll
    for (int m = 1; m < 64; m <<= 1) { s += __shfl_xor(s, m); ss += __shfl_xor(ss, m); }
    float mean = s * (1.f / 96.f);
    float var = (ss - 96.f * mean * mean) * (1.f / 95.f);
    var = fmaxf(var, 0.f);
    float inv = 1.f / (sqrtf(var) + 1e-8f);
    unsigned short* orow = rec + (size_t)n * 384 + 256;
    orow[lane] = f2bf((v0 - mean) * inv);
    if (lane < 32) orow[64 + lane] = f2bf((v1 - mean) * inv);
}

// ---------------- CSR build: histogram(+rank) / 3-stage scan / atomic-free scatter ----------
__global__ __launch_bounds__(256) void k_hist(const int* __restrict__ ei,
                                              int* __restrict__ deg,
                                              int* __restrict__ rnk, int E0, int N)
{
    int e = blockIdx.x * 256 + threadIdx.x;
    int E = E0 + N;
    if (e >= E) return;
    int dst = (e < E0) ? ei[E0 + e] : (e - E0);
    rnk[e] = atomicAdd(&deg[dst], 1);
}

__global__ __launch_bounds__(256) void k_scanA(const int* __restrict__ deg,
                                               int* __restrict__ bsum, int N)
{
    __shared__ int sm[256];
    int i = blockIdx.x * 256 + threadIdx.x;
    sm[threadIdx.x] = (i < N) ? deg[i] : 0;
    __syncthreads();
    for (int off = 128; off > 0; off >>= 1) {
        if (threadIdx.x < off) sm[threadIdx.x] += sm[threadIdx.x + off];
        __syncthreads();
    }
    if (threadIdx.x == 0) bsum[blockIdx.x] = sm[0];
}

__global__ __launch_bounds__(256) void k_scanB(int* __restrict__ bsum, int NB)
{
    __shared__ int sm[256];
    int t = threadIdx.x;
    sm[t] = (t < NB) ? bsum[t] : 0;
    __syncthreads();
    for (int off = 1; off < 256; off <<= 1) {
        int v = (t >= off) ? sm[t - off] : 0;
        __syncthreads();
        sm[t] += v;
        __syncthreads();
    }
    if (t < NB) bsum[t] = (t == 0) ? 0 : sm[t - 1];
}

__global__ __launch_bounds__(256) void k_scanC(const int* __restrict__ deg,
                                               const int* __restrict__ bsum,
                                               int* __restrict__ row, int N)
{
    __shared__ int sm[256];
    int b = blockIdx.x, t = threadIdx.x, i = b * 256 + t;
    int v = (i < N) ? deg[i] : 0;
    sm[t] = v;
    __syncthreads();
    for (int off = 1; off < 256; off <<= 1) {
        int u = (t >= off) ? sm[t - off] : 0;
        __syncthreads();
        sm[t] += u;
        __syncthreads();
    }
    int excl = bsum[b] + sm[t] - v;
    if (i < N) {
        row[i] = excl;
        if (i == N - 1) row[N] = excl + v;
    }
}

__global__ __launch_bounds__(256) void k_scatter(const int* __restrict__ ei,
                                                 const int* __restrict__ row,
                                                 const int* __restrict__ rnk,
                                                 int2* __restrict__ csrd, int E0, int N)
{
    int e = blockIdx.x * 256 + threadIdx.x;
    int E = E0 + N;
    if (e >= E) return;
    int src, dst;
    if (e < E0) { src = ei[e]; dst = ei[E0 + e]; }
    else        { src = e - E0; dst = src; }
    int pos = row[dst] + rnk[e];
    csrd[pos] = make_int2(e, src);
}

// ---------------- fused per-node attention: chunked online softmax, all-register ----------
// one wave per node (4/block). lane = g*8+h: group g = edge slot, h = head (phase L)
// and h = channel block (accumulate). All src data from the node's 768B record.
__global__ __launch_bounds__(256) void k_nodeattn(
    const int2* __restrict__ csrd, const int* __restrict__ row,
    const float* __restrict__ eattr,
    const float* __restrict__ q, const unsigned short* __restrict__ rec,
    const float* __restrict__ Wo, const float* __restrict__ bo,
    float* __restrict__ out, int E0, int N)
{
    const int tid = threadIdx.x;
    const int wave = tid >> 6, lane = tid & 63;
    const int n = blockIdx.x * 4 + wave;
    if (n >= N) return;

    const int beg = row[n], end = row[n + 1];
    const int h = lane & 7;           // head / channel block
    const int g = lane >> 3;          // edge slot
    const int koff = h * 8;           // per-lane record offsets (ushorts)
    const int goff = 64 + h * 16;
    const int voff = 192 + h * 8;
    const int toff = 256 + h * 12;

    // hoisted dst-side data (per head h) from own record
    const unsigned short* recN = rec + (size_t)n * 384;
    const float4* qp = (const float4*)(q + (size_t)n * 64 + h * 8);
    const float4 qd0 = qp[0], qd1 = qp[1];
    const uint2* tdp = (const uint2*)(recN + toff);
    const uint2 td0 = tdp[0], td1 = tdp[1], td2 = tdp[2];
    const float bnh = ((const float*)(recN + 368))[h];

    float m_reg = -1e30f, dsum = 0.f;
    float acc[8];
    #pragma unroll
    for (int c = 0; c < 8; c++) acc[c] = 0.f;

    for (int cbeg = beg; cbeg < end; cbeg += CH) {
        const int cnt = min(CH, end - cbeg);

        float av[4];
        uint4 vu[4];
        // ---- phase L: logits + vb prefetch for this chunk (registers only) ----
        #pragma unroll
        for (int j = 0; j < 4; j++) {
            av[j] = -1e30f;
            vu[j] = make_uint4(0u, 0u, 0u, 0u);
            int eo = g + 8 * j;
            if (eo < cnt) {
                int2 es = csrd[cbeg + eo];
                const int e = es.x, s = es.y;
                const unsigned short* recS = rec + (size_t)s * 384;

                vu[j] = *(const uint4*)(recS + voff);   // prefetch V

                const US4* kp = (const US4*)(recS + koff);
                US4 k0 = kp[0], k1 = kp[1];
                float qk = qd0.x*bf2f(k0.x) + qd0.y*bf2f(k0.y) + qd0.z*bf2f(k0.z) + qd0.w*bf2f(k0.w)
                         + qd1.x*bf2f(k1.x) + qd1.y*bf2f(k1.y) + qd1.z*bf2f(k1.z) + qd1.w*bf2f(k1.w);

                const uint4* gp = (const uint4*)(recS + goff);
                uint4 g0 = gp[0], g1 = gp[1];
                int ec = (e < E0) ? e : 0;
                const float4* ep4 = (const float4*)(eattr + (size_t)ec * 16);
                float4 e0 = ep4[0], e1 = ep4[1], e2 = ep4[2], e3 = ep4[3];
                if (e >= E0) {
                    e0 = make_float4(1.f, 1.f, 1.f, 1.f); e1 = e0; e2 = e0; e3 = e0;
                }
                float efk = e0.x*blo(g0.x) + e0.y*bhi(g0.x) + e0.z*blo(g0.y) + e0.w*bhi(g0.y)
                          + e1.x*blo(g0.z) + e1.y*bhi(g0.z) + e1.z*blo(g0.w) + e1.w*bhi(g0.w)
                          + e2.x*blo(g1.x) + e2.y*bhi(g1.x) + e2.z*blo(g1.y) + e2.w*bhi(g1.y)
                          + e3.x*blo(g1.z) + e3.y*bhi(g1.z) + e3.z*blo(g1.w) + e3.w*bhi(g1.w);

                float tv = ((const float*)(recS + 352))[h] + bnh;
                float ex = __expf(2.f * tv);
                float tn = 1.f - 2.f / (ex + 1.f);

                const uint2* tsp = (const uint2*)(recS + toff);
                uint2 s0 = tsp[0], s1 = tsp[1], s2 = tsp[2];
                float pc = blo(s0.x)*blo(td0.x) + bhi(s0.x)*bhi(td0.x)
                         + blo(s0.y)*blo(td0.y) + bhi(s0.y)*bhi(td0.y)
                         + blo(s1.x)*blo(td1.x) + bhi(s1.x)*bhi(td1.x)
                         + blo(s1.y)*blo(td1.y) + bhi(s1.y)*bhi(td1.y)
                         + blo(s2.x)*blo(td2.x) + bhi(s2.x)*bhi(td2.x)
                         + blo(s2.y)*blo(td2.y) + bhi(s2.y)*bhi(td2.y);
                float cv = pc * (-0.25f / 96.f) + tn * (-0.25f / 8.f);
                cv += __shfl_xor(cv, 1); cv += __shfl_xor(cv, 2); cv += __shfl_xor(cv, 4);

                float a = qk + efk + cv;
                av[j] = fmaxf(a, 0.2f * a);            // leaky relu
            }
        }

        // ---- chunk max per head (across groups: lane bits 3-5) ----
        float mloc = fmaxf(fmaxf(av[0], av[1]), fmaxf(av[2], av[3]));
        mloc = fmaxf(mloc, __shfl_xor(mloc, 8));
        mloc = fmaxf(mloc, __shfl_xor(mloc, 16));
        mloc = fmaxf(mloc, __shfl_xor(mloc, 32));

        // ---- online merge + accumulate (all register) ----
        float mn = fmaxf(m_reg, mloc);
        float sc = __expf(m_reg - mn);
        m_reg = mn;
        dsum *= sc;
        #pragma unroll
        for (int c = 0; c < 8; c++) acc[c] *= sc;

        #pragma unroll
        for (int j = 0; j < 4; j++) {
            float p = __expf(av[j] - mn);              // 0 for inactive slots
            dsum += p;
            acc[0] += p * blo(vu[j].x); acc[1] += p * bhi(vu[j].x);
            acc[2] += p * blo(vu[j].y); acc[3] += p * bhi(vu[j].y);
            acc[4] += p * blo(vu[j].z); acc[5] += p * bhi(vu[j].z);
            acc[6] += p * blo(vu[j].w); acc[7] += p * bhi(vu[j].w);
        }
    }

    // ---- merge slots (bits 3-5): per-head denom + channel sums ----
    dsum += __shfl_xor(dsum, 8); dsum += __shfl_xor(dsum, 16); dsum += __shfl_xor(dsum, 32);
    #pragma unroll
    for (int c = 0; c < 8; c++) {
        acc[c] += __shfl_xor(acc[c], 8);
        acc[c] += __shfl_xor(acc[c], 16);
        acc[c] += __shfl_xor(acc[c], 32);
    }
    float inv = 1.f / (dsum + 1e-16f);

    // ---- fused Wo projection: lane holds channels h*8..h*8+7 ----
    float po[8];
    #pragma unroll
    for (int cp8 = 0; cp8 < 8; cp8++) {
        const float4* wr = (const float4*)(Wo + cp8 * 64 + h * 8);
        float4 w0 = wr[0], w1 = wr[1];
        po[cp8] = inv * (acc[0]*w0.x + acc[1]*w0.y + acc[2]*w0.z + acc[3]*w0.w
                       + acc[4]*w1.x + acc[5]*w1.y + acc[6]*w1.z + acc[7]*w1.w);
    }
    #pragma unroll
    for (int cp8 = 0; cp8 < 8; cp8++) {
        po[cp8] += __shfl_xor(po[cp8], 1);
        po[cp8] += __shfl_xor(po[cp8], 2);
        po[cp8] += __shfl_xor(po[cp8], 4);
    }
    if (lane < 8) out[(size_t)n * 8 + lane] = po[lane] + bo[lane];
}

extern "C" void kernel_launch(void* const* d_in, const int* in_sizes, int n_in,
                              void* d_out, int out_size, void* d_ws, size_t ws_size,
                              hipStream_t stream)
{
    const float* x     = (const float*)d_in[0];
    const int*   ei    = (const int*)d_in[1];
    const float* eattr = (const float*)d_in[2];
    const float* tp    = (const float*)d_in[3];
    const float* Wq    = (const float*)d_in[4];
    const float* Wk    = (const float*)d_in[5];
    const float* Wv    = (const float*)d_in[6];
    const float* We    = (const float*)d_in[7];
    const float* compW = (const float*)d_in[8];
    const float* compb = (const float*)d_in[9];
    const float* Wo    = (const float*)d_in[10];
    const float* bo    = (const float*)d_in[11];
    float* out = (float*)d_out;

    const int N  = in_sizes[0] / 128;
    const int E0 = in_sizes[1] / 2;
    const int E  = E0 + N;
    const int NB = (N + 255) / 256;

    float* ws = (float*)d_ws;
    size_t off = 0;
    unsigned short* rec = (unsigned short*)(ws + off); off += (size_t)N * 192;   // N x 768B records
    float* q  = ws + off; off += (size_t)N * 64;
    int* deg    = (int*)(ws + off); off += N;
    int* bsum   = (int*)(ws + off); off += 256;
    int* rowp   = (int*)(ws + off); off += N + 4;
    unsigned short* Bp = (unsigned short*)(ws + off); off += 21504;              // 43008 ushort
    int2* csrd  = (int2*)(ws + off); off += (size_t)E * 2;
    int* rnk    = (int*)(ws + off); off += E;

    hipMemsetAsync(deg, 0, (size_t)N * sizeof(int), stream);

    k_hist<<<(E + 255) / 256, 256, 0, stream>>>(ei, deg, rnk, E0, N);
    k_scanA<<<NB, 256, 0, stream>>>(deg, bsum, N);
    k_scanB<<<1, 256, 0, stream>>>(bsum, NB);
    k_scanC<<<NB, 256, 0, stream>>>(deg, bsum, rowp, N);
    k_scatter<<<(E + 255) / 256, 256, 0, stream>>>(ei, rowp, rnk, csrd, E0, N);

    k_bpack<<<(21 * 2048 + 255) / 256, 256, 0, stream>>>(Wq, Wk, Wv, compW, We, Bp);
    k_gemm<<<(N + 63) / 64, 256, 0, stream>>>(x, Bp, compb, q, rec, N);
    k_tpn<<<(N + 3) / 4, 256, 0, stream>>>(tp, rec, N);

    k_nodeattn<<<(N + 3) / 4, 256, 0, stream>>>(csrd, rowp, eattr, q, rec,
                                                Wo, bo, out, E0, N);
}